// Round 11
// baseline (314.346 us; speedup 1.0000x reference)
//
#include <hip/hip_runtime.h>

// Per-row MLP 5->120->84->5 + relu + L2-normalize + x!=0 mask.
// R11 = R10 (zero-LDS swapped-operand MFMA, register-resident weights)
//  + occupancy x2 (1024 blocks, launch_bounds(256,4): 16 waves/CU at 96 VGPR)
//  + 1-deep software pipeline on the x-load (prefetch tile t+nw before
//    computing tile t; waitcnt sinks to next iteration's register copy)
//  + TAU2 0.0625 -> 0.04 (smaller rescue set; normalized f16 err at
//    ||y||=0.2 is ~1e-2, 2x under the 2e-2 threshold).

typedef _Float16 f16x8 __attribute__((ext_vector_type(8)));
typedef float    f32x4 __attribute__((ext_vector_type(4)));

#define CNT_OFF  0
#define W2T_OFF  64          // f32[120*84]          -> ends 40384
#define W1A_OFF  40384       // f16[8][64][8]        -> ends 48576
#define W2A_OFF  48576       // f16[24][64][8]       -> ends 73152
#define W3A_OFF  73152       // f16[3][64][8]        -> ends 76224
#define LIST_OFF 76224
#define TAU2     0.04f       // rescue if ||y||^2 < 0.2^2

// ---------------- pack ----------------
__global__ __launch_bounds__(256) void pack_kernel(
    const float* __restrict__ W1, const float* __restrict__ b1,
    const float* __restrict__ W2, const float* __restrict__ b2,
    const float* __restrict__ W3, const float* __restrict__ b3,
    char* __restrict__ ws)
{
    int i = blockIdx.x * 256 + threadIdx.x;
    if (i == 0) *(unsigned int*)(ws + CNT_OFF) = 0u;
    _Float16* W1a = (_Float16*)(ws + W1A_OFF);
    _Float16* W2a = (_Float16*)(ws + W2A_OFF);
    _Float16* W3a = (_Float16*)(ws + W3A_OFF);
    float*    W2T = (float*)(ws + W2T_OFF);

    // W1a[n][l][j]: A-frag of W1aug. feat = 16n + (l&15), k = (l>>4)*8 + j.
    if (i < 4096) {
        int n = i >> 9, l = (i >> 3) & 63, j = i & 7;
        int feat = 16*n + (l & 15);
        int k = (l >> 4) * 8 + j;
        float v = 0.f;
        if (feat < 120) {
            if (k < 5) v = W1[feat*5 + k];
            else if (k == 5) v = b1[feat];
        } else if (feat == 120 && k == 5) v = 1.f;
        W1a[i] = (_Float16)v;
    }
    // W2a[b=(n2*4+t4)][l][j']: A-frag of W2aug, k-permuted:
    //   f = 32*t4 + 16*(j'>>2) + 4*(l>>4) + (j'&3)
    if (i < 12288) {
        int b = i >> 9, l = (i >> 3) & 63, j = i & 7;
        int n2 = b >> 2, t4 = b & 3;
        int g = 16*n2 + (l & 15);
        int f = 32*t4 + 16*(j >> 2) + 4*(l >> 4) + (j & 3);
        float v = 0.f;
        if (g < 84) {
            if (f < 120) v = W2[g*120 + f];
            else if (f == 120) v = b2[g];
        } else if (g == 84 && f == 120) v = 1.f;
        W2a[i] = (_Float16)v;
    }
    // W3a[t3][l][j']: A-frag of W3aug, same k-permutation over h2 features.
    if (i < 1536) {
        int t3 = i >> 9, l = (i >> 3) & 63, j = i & 7;
        int o = l & 15;
        int f = 32*t3 + 16*(j >> 2) + 4*(l >> 4) + (j & 3);
        float v = 0.f;
        if (o < 5) {
            if (f < 84) v = W3[o*84 + f];
            else if (f == 84) v = b3[o];
        }
        W3a[i] = (_Float16)v;
    }
    // W2T for the f32 rescue path.
    if (i < 10080) { int g = i / 120, h = i - g*120; W2T[h*84 + g] = W2[i]; }
}

// ---------------- main (persistent, zero-LDS, x-prefetch) ----------------
__global__ __launch_bounds__(256, 4) void mfma_main(
    const float* __restrict__ x, const char* __restrict__ ws,
    float* __restrict__ out,
    unsigned int* __restrict__ cnt, unsigned int* __restrict__ list,
    unsigned int cap, int nrows, int ntiles)
{
    const _Float16* W1a = (const _Float16*)(ws + W1A_OFF);
    const _Float16* W2a = (const _Float16*)(ws + W2A_OFF);
    const _Float16* W3a = (const _Float16*)(ws + W3A_OFF);

    const int tid  = threadIdx.x;
    const int w    = tid >> 6, lane = tid & 63;
    const int c    = lane & 15, q = lane >> 4;

    // persistent weight fragments (loaded once per wave)
    f16x8 w1f[8], w2f[24], w3f[3];
#pragma unroll
    for (int n = 0; n < 8; ++n)  w1f[n] = *(const f16x8*)(W1a + (n*64 + lane)*8);
#pragma unroll
    for (int b = 0; b < 24; ++b) w2f[b] = *(const f16x8*)(W2a + (b*64 + lane)*8);
#pragma unroll
    for (int t = 0; t < 3; ++t)  w3f[t] = *(const f16x8*)(W3a + (t*64 + lane)*8);

    const int gw = blockIdx.x * 4 + w;
    const int nw = gridDim.x * 4;

    // prefetch x for the first tile
    float nx0 = 0.f, nx1 = 0.f, nx2 = 0.f, nx3 = 0.f, nx4 = 0.f;
    {
        long r0 = (long)gw * 16 + c;
        if (q == 0 && gw < ntiles && r0 < nrows) {
            const float* xp = x + r0 * 5;
            nx0 = xp[0]; nx1 = xp[1]; nx2 = xp[2]; nx3 = xp[3]; nx4 = xp[4];
        }
    }

    for (int t = gw; t < ntiles; t += nw) {
        const long row = (long)t * 16 + c;
        const bool valid = (q == 0) && (row < nrows);

        // consume prefetched x
        const float xv0 = nx0, xv1 = nx1, xv2 = nx2, xv3 = nx3, xv4 = nx4;

        // issue next tile's loads NOW (hidden under this tile's compute)
        nx0 = nx1 = nx2 = nx3 = nx4 = 0.f;
        {
            const int tn = t + nw;
            long rn = (long)tn * 16 + c;
            if (q == 0 && tn < ntiles && rn < nrows) {
                const float* xp = x + rn * 5;
                nx0 = xp[0]; nx1 = xp[1]; nx2 = xp[2]; nx3 = xp[3]; nx4 = xp[4];
            }
        }

        // B-frag of xaug^T: lane holds xaug[c][k=q*8+j]; q==0: [x0..x4,1,0,0]
        f16x8 ax;
#pragma unroll
        for (int j = 0; j < 8; ++j) ax[j] = (_Float16)0.f;
        if (valid) {
            ax[0] = (_Float16)xv0; ax[1] = (_Float16)xv1; ax[2] = (_Float16)xv2;
            ax[3] = (_Float16)xv3; ax[4] = (_Float16)xv4; ax[5] = (_Float16)1.f;
        }

        // ---- L1: d1[n] = W1aug . xaug^T (lane: feats 16n+4q+j of row c) ----
        f32x4 d1[8];
#pragma unroll
        for (int n = 0; n < 8; ++n)
            d1[n] = __builtin_amdgcn_mfma_f32_16x16x32_f16(
                w1f[n], ax, (f32x4){0.f, 0.f, 0.f, 0.f}, 0, 0, 0);

        // ---- pack h1 B-frags (relu + cvt), k-order matches W2a's perm ----
        f16x8 pb[4];
#pragma unroll
        for (int t4 = 0; t4 < 4; ++t4) {
#pragma unroll
            for (int j = 0; j < 4; ++j) {
                pb[t4][j]     = (_Float16)fmaxf(d1[2*t4][j],     0.f);
                pb[t4][j + 4] = (_Float16)fmaxf(d1[2*t4 + 1][j], 0.f);
            }
        }

        // ---- L2: acc[n2] = W2aug . h1^T ----
        f32x4 acc[6];
#pragma unroll
        for (int n2 = 0; n2 < 6; ++n2) acc[n2] = (f32x4){0.f, 0.f, 0.f, 0.f};
#pragma unroll
        for (int t4 = 0; t4 < 4; ++t4)
#pragma unroll
            for (int n2 = 0; n2 < 6; ++n2)
                acc[n2] = __builtin_amdgcn_mfma_f32_16x16x32_f16(
                    w2f[n2*4 + t4], pb[t4], acc[n2], 0, 0, 0);

        // ---- pack h2 B-frags ----
        f16x8 ph[3];
#pragma unroll
        for (int t3 = 0; t3 < 3; ++t3) {
#pragma unroll
            for (int j = 0; j < 4; ++j) {
                ph[t3][j]     = (_Float16)fmaxf(acc[2*t3][j],     0.f);
                ph[t3][j + 4] = (_Float16)fmaxf(acc[2*t3 + 1][j], 0.f);
            }
        }

        // ---- L3: acy = W3aug . h2^T (lane: outs 4q+j of row c) ----
        f32x4 acy = (f32x4){0.f, 0.f, 0.f, 0.f};
#pragma unroll
        for (int t3 = 0; t3 < 3; ++t3)
            acy = __builtin_amdgcn_mfma_f32_16x16x32_f16(
                w3f[t3], ph[t3], acy, 0, 0, 0);

        // ---- epilogue ----
        float r0 = fmaxf(acy[0], 0.f);
        float y4 = __shfl(r0, c + 16, 64);       // out4 lives in q==1, j==0
        if (valid) {
            float y0 = r0;
            float y1 = fmaxf(acy[1], 0.f);
            float y2 = fmaxf(acy[2], 0.f);
            float y3 = fmaxf(acy[3], 0.f);
            float ss = y0*y0 + y1*y1 + y2*y2 + y3*y3 + y4*y4;
            float inv = 1.0f / fmaxf(sqrtf(ss), 1e-12f);
            float* op = out + row * 5;
            op[0] = (xv0 != 0.f) ? 0.f : y0 * inv;
            op[1] = (xv1 != 0.f) ? 0.f : y1 * inv;
            op[2] = (xv2 != 0.f) ? 0.f : y2 * inv;
            op[3] = (xv3 != 0.f) ? 0.f : y3 * inv;
            op[4] = (xv4 != 0.f) ? 0.f : y4 * inv;
            if (ss < TAU2) {
                unsigned int idx = atomicAdd(cnt, 1u);
                if (idx < cap) list[idx] = (unsigned int)row;
            }
        }
    }
}

// ---------------- rescue (exact f32, R3 structure) ----------------
template <int G0>
__device__ __forceinline__ void half_pass(
    const float xv[5],
    const float* __restrict__ W1, const float* __restrict__ b1,
    const float* __restrict__ W2T, const float* __restrict__ b2,
    const float* __restrict__ W3,
    float y[5])
{
    float acc[42];
#pragma unroll
    for (int g = 0; g < 42; ++g) acc[g] = b2[G0 + g];
    for (int h = 0; h < 120; ++h) {
        float a = b1[h];
        a = fmaf(W1[h*5 + 0], xv[0], a);
        a = fmaf(W1[h*5 + 1], xv[1], a);
        a = fmaf(W1[h*5 + 2], xv[2], a);
        a = fmaf(W1[h*5 + 3], xv[3], a);
        a = fmaf(W1[h*5 + 4], xv[4], a);
        a = fmaxf(a, 0.0f);
        const float* wr = W2T + h*84 + G0;
#pragma unroll
        for (int g = 0; g < 42; ++g) acc[g] = fmaf(wr[g], a, acc[g]);
    }
#pragma unroll
    for (int g = 0; g < 42; ++g) acc[g] = fmaxf(acc[g], 0.0f);
#pragma unroll
    for (int o = 0; o < 5; ++o) {
        const float* w3o = W3 + o*84 + G0;
        float ty = y[o];
#pragma unroll
        for (int g = 0; g < 42; ++g) ty = fmaf(w3o[g], acc[g], ty);
        y[o] = ty;
    }
}

__global__ __launch_bounds__(256) void rescue_kernel(
    const float* __restrict__ x,
    const float* __restrict__ W1, const float* __restrict__ b1,
    const char*  __restrict__ ws, const float* __restrict__ b2,
    const float* __restrict__ W3, const float* __restrict__ b3,
    float* __restrict__ out, unsigned int cap, int nrows)
{
    const unsigned int* cnt  = (const unsigned int*)(ws + CNT_OFF);
    const unsigned int* list = (const unsigned int*)(ws + LIST_OFF);
    const float* W2T = (const float*)(ws + W2T_OFF);
    unsigned int count = *cnt;
    if (count > cap) count = cap;

    for (unsigned int t = blockIdx.x * 256 + threadIdx.x;
         t < count; t += gridDim.x * 256) {
        long row = (long)list[t];
        if (row < 0 || row >= (long)nrows) continue;   // replay-safety guard

        const float* xr = x + row * 5;
        float xv[5];
#pragma unroll
        for (int i = 0; i < 5; ++i) xv[i] = xr[i];

        float y[5];
#pragma unroll
        for (int o = 0; o < 5; ++o) y[o] = b3[o];
        half_pass<0>(xv, W1, b1, W2T, b2, W3, y);
        half_pass<42>(xv, W1, b1, W2T, b2, W3, y);
#pragma unroll
        for (int o = 0; o < 5; ++o) y[o] = fmaxf(y[o], 0.0f);

        float ss = y[0]*y[0];
        ss = fmaf(y[1], y[1], ss);
        ss = fmaf(y[2], y[2], ss);
        ss = fmaf(y[3], y[3], ss);
        ss = fmaf(y[4], y[4], ss);
        float inv = 1.0f / fmaxf(sqrtf(ss), 1e-12f);
        float* op = out + row * 5;
#pragma unroll
        for (int o = 0; o < 5; ++o)
            op[o] = (xv[o] != 0.f) ? 0.f : y[o] * inv;
    }
}

// ---------------- launch ----------------
extern "C" void kernel_launch(void* const* d_in, const int* in_sizes, int n_in,
                              void* d_out, int out_size, void* d_ws, size_t ws_size,
                              hipStream_t stream) {
    const float* x  = (const float*)d_in[0];
    const float* W1 = (const float*)d_in[1];
    const float* b1 = (const float*)d_in[2];
    const float* W2 = (const float*)d_in[3];
    const float* b2 = (const float*)d_in[4];
    const float* W3 = (const float*)d_in[5];
    const float* b3 = (const float*)d_in[6];
    float* out = (float*)d_out;
    char* ws = (char*)d_ws;

    const int nrows = in_sizes[0] / 5;
    const int ntiles = (nrows + 15) / 16;
    unsigned int cap = (ws_size > (size_t)LIST_OFF + 4)
                       ? (unsigned int)((ws_size - LIST_OFF) / 4) : 0u;
    unsigned int* cnt  = (unsigned int*)(ws + CNT_OFF);
    unsigned int* list = (unsigned int*)(ws + LIST_OFF);

    pack_kernel<<<48, 256, 0, stream>>>(W1, b1, W2, b2, W3, b3, ws);

    mfma_main<<<1024, 256, 0, stream>>>(x, ws, out, cnt, list, cap,
                                        nrows, ntiles);

    rescue_kernel<<<256, 256, 0, stream>>>(x, W1, b1, ws, b2, W3, b3,
                                           out, cap, nrows);
}

// Round 12
// 140.747 us; speedup vs baseline: 2.2334x; 2.2334x over previous
//
#include <hip/hip_runtime.h>

// Per-row MLP 5->120->84->5 + relu + L2-normalize + x!=0 mask.
// R12 = R10 (zero-LDS swapped-operand MFMA, register/AGPR-resident weights,
// launch_bounds(256,2), 512 blocks) + 2-TILE INTERLEAVE per wave iteration:
// tiles (2p, 2p+1) computed together; their MFMA/VALU chains are independent
// so the scheduler overlaps them, ~halving exposed latency (R10 was
// latency-bound at 2 waves/SIMD; R11 proved occupancy can't rise without
// spilling the 140-VGPR weight set -- FETCH exploded 13->790 MB).
// h1-pack fused into the L1 loop to keep only 2 d1 temporaries live/tile.
// x prefetched one pair ahead. TAU2=0.04 rescue via exact-f32 kernel.

typedef _Float16 f16x8 __attribute__((ext_vector_type(8)));
typedef float    f32x4 __attribute__((ext_vector_type(4)));

#define CNT_OFF  0
#define W2T_OFF  64          // f32[120*84]          -> ends 40384
#define W1A_OFF  40384       // f16[8][64][8]        -> ends 48576
#define W2A_OFF  48576       // f16[24][64][8]       -> ends 73152
#define W3A_OFF  73152       // f16[3][64][8]        -> ends 76224
#define LIST_OFF 76224
#define TAU2     0.04f       // rescue if ||y||^2 < 0.2^2

// ---------------- pack ----------------
__global__ __launch_bounds__(256) void pack_kernel(
    const float* __restrict__ W1, const float* __restrict__ b1,
    const float* __restrict__ W2, const float* __restrict__ b2,
    const float* __restrict__ W3, const float* __restrict__ b3,
    char* __restrict__ ws)
{
    int i = blockIdx.x * 256 + threadIdx.x;
    if (i == 0) *(unsigned int*)(ws + CNT_OFF) = 0u;
    _Float16* W1a = (_Float16*)(ws + W1A_OFF);
    _Float16* W2a = (_Float16*)(ws + W2A_OFF);
    _Float16* W3a = (_Float16*)(ws + W3A_OFF);
    float*    W2T = (float*)(ws + W2T_OFF);

    // W1a[n][l][j]: A-frag of W1aug. feat = 16n + (l&15), k = (l>>4)*8 + j.
    if (i < 4096) {
        int n = i >> 9, l = (i >> 3) & 63, j = i & 7;
        int feat = 16*n + (l & 15);
        int k = (l >> 4) * 8 + j;
        float v = 0.f;
        if (feat < 120) {
            if (k < 5) v = W1[feat*5 + k];
            else if (k == 5) v = b1[feat];
        } else if (feat == 120 && k == 5) v = 1.f;
        W1a[i] = (_Float16)v;
    }
    // W2a[b=(n2*4+t4)][l][j']: A-frag of W2aug, k-permuted:
    //   f = 32*t4 + 16*(j'>>2) + 4*(l>>4) + (j'&3)
    if (i < 12288) {
        int b = i >> 9, l = (i >> 3) & 63, j = i & 7;
        int n2 = b >> 2, t4 = b & 3;
        int g = 16*n2 + (l & 15);
        int f = 32*t4 + 16*(j >> 2) + 4*(l >> 4) + (j & 3);
        float v = 0.f;
        if (g < 84) {
            if (f < 120) v = W2[g*120 + f];
            else if (f == 120) v = b2[g];
        } else if (g == 84 && f == 120) v = 1.f;
        W2a[i] = (_Float16)v;
    }
    // W3a[t3][l][j']: A-frag of W3aug, same k-permutation over h2 features.
    if (i < 1536) {
        int t3 = i >> 9, l = (i >> 3) & 63, j = i & 7;
        int o = l & 15;
        int f = 32*t3 + 16*(j >> 2) + 4*(l >> 4) + (j & 3);
        float v = 0.f;
        if (o < 5) {
            if (f < 84) v = W3[o*84 + f];
            else if (f == 84) v = b3[o];
        }
        W3a[i] = (_Float16)v;
    }
    // W2T for the f32 rescue path.
    if (i < 10080) { int g = i / 120, h = i - g*120; W2T[h*84 + g] = W2[i]; }
}

// ---------------- main (persistent, zero-LDS, 2-tile interleave) ----------
__global__ __launch_bounds__(256, 2) void mfma_main(
    const float* __restrict__ x, const char* __restrict__ ws,
    float* __restrict__ out,
    unsigned int* __restrict__ cnt, unsigned int* __restrict__ list,
    unsigned int cap, int nrows, int npairs)
{
    const _Float16* W1a = (const _Float16*)(ws + W1A_OFF);
    const _Float16* W2a = (const _Float16*)(ws + W2A_OFF);
    const _Float16* W3a = (const _Float16*)(ws + W3A_OFF);

    const int tid  = threadIdx.x;
    const int w    = tid >> 6, lane = tid & 63;
    const int c    = lane & 15, q = lane >> 4;

    // persistent weight fragments (loaded once per wave; live in VGPR/AGPR)
    f16x8 w1f[8], w2f[24], w3f[3];
#pragma unroll
    for (int n = 0; n < 8; ++n)  w1f[n] = *(const f16x8*)(W1a + (n*64 + lane)*8);
#pragma unroll
    for (int b = 0; b < 24; ++b) w2f[b] = *(const f16x8*)(W2a + (b*64 + lane)*8);
#pragma unroll
    for (int t = 0; t < 3; ++t)  w3f[t] = *(const f16x8*)(W3a + (t*64 + lane)*8);

    const int gw = blockIdx.x * 4 + w;
    const int nw = gridDim.x * 4;

    // prefetch x for the first pair (tiles 2p and 2p+1 -> rows 32p+c, +16)
    float nxA[5] = {0.f, 0.f, 0.f, 0.f, 0.f};
    float nxB[5] = {0.f, 0.f, 0.f, 0.f, 0.f};
    if (q == 0 && gw < npairs) {
        long rA = (long)gw * 32 + c;
        long rB = rA + 16;
        if (rA < nrows) {
            const float* xp = x + rA * 5;
            nxA[0]=xp[0]; nxA[1]=xp[1]; nxA[2]=xp[2]; nxA[3]=xp[3]; nxA[4]=xp[4];
        }
        if (rB < nrows) {
            const float* xp = x + rB * 5;
            nxB[0]=xp[0]; nxB[1]=xp[1]; nxB[2]=xp[2]; nxB[3]=xp[3]; nxB[4]=xp[4];
        }
    }

    for (int p = gw; p < npairs; p += nw) {
        const long rowA = (long)p * 32 + c;
        const long rowB = rowA + 16;
        const bool validA = (q == 0) && (rowA < nrows);
        const bool validB = (q == 0) && (rowB < nrows);

        // consume prefetched x
        float xA[5], xB[5];
#pragma unroll
        for (int i = 0; i < 5; ++i) { xA[i] = nxA[i]; xB[i] = nxB[i]; }

        // issue next pair's loads now (hidden under this pair's compute)
#pragma unroll
        for (int i = 0; i < 5; ++i) { nxA[i] = 0.f; nxB[i] = 0.f; }
        {
            const int pn = p + nw;
            if (q == 0 && pn < npairs) {
                long rA = (long)pn * 32 + c;
                long rB = rA + 16;
                if (rA < nrows) {
                    const float* xp = x + rA * 5;
                    nxA[0]=xp[0]; nxA[1]=xp[1]; nxA[2]=xp[2]; nxA[3]=xp[3]; nxA[4]=xp[4];
                }
                if (rB < nrows) {
                    const float* xp = x + rB * 5;
                    nxB[0]=xp[0]; nxB[1]=xp[1]; nxB[2]=xp[2]; nxB[3]=xp[3]; nxB[4]=xp[4];
                }
            }
        }

        // B-frags of xaug^T
        f16x8 axA, axB;
#pragma unroll
        for (int j = 0; j < 8; ++j) { axA[j] = (_Float16)0.f; axB[j] = (_Float16)0.f; }
        if (validA) {
            axA[0]=(_Float16)xA[0]; axA[1]=(_Float16)xA[1]; axA[2]=(_Float16)xA[2];
            axA[3]=(_Float16)xA[3]; axA[4]=(_Float16)xA[4]; axA[5]=(_Float16)1.f;
        }
        if (validB) {
            axB[0]=(_Float16)xB[0]; axB[1]=(_Float16)xB[1]; axB[2]=(_Float16)xB[2];
            axB[3]=(_Float16)xB[3]; axB[4]=(_Float16)xB[4]; axB[5]=(_Float16)1.f;
        }

        // ---- L1 + fused h1-pack: pb*[t4] B-frags (k-order = W2a's perm) ----
        f16x8 pbA[4], pbB[4];
#pragma unroll
        for (int t4 = 0; t4 < 4; ++t4) {
            f32x4 dA0 = __builtin_amdgcn_mfma_f32_16x16x32_f16(
                w1f[2*t4],     axA, (f32x4){0.f,0.f,0.f,0.f}, 0, 0, 0);
            f32x4 dB0 = __builtin_amdgcn_mfma_f32_16x16x32_f16(
                w1f[2*t4],     axB, (f32x4){0.f,0.f,0.f,0.f}, 0, 0, 0);
            f32x4 dA1 = __builtin_amdgcn_mfma_f32_16x16x32_f16(
                w1f[2*t4 + 1], axA, (f32x4){0.f,0.f,0.f,0.f}, 0, 0, 0);
            f32x4 dB1 = __builtin_amdgcn_mfma_f32_16x16x32_f16(
                w1f[2*t4 + 1], axB, (f32x4){0.f,0.f,0.f,0.f}, 0, 0, 0);
#pragma unroll
            for (int j = 0; j < 4; ++j) {
                pbA[t4][j]     = (_Float16)fmaxf(dA0[j], 0.f);
                pbA[t4][j + 4] = (_Float16)fmaxf(dA1[j], 0.f);
                pbB[t4][j]     = (_Float16)fmaxf(dB0[j], 0.f);
                pbB[t4][j + 4] = (_Float16)fmaxf(dB1[j], 0.f);
            }
        }

        // ---- L2: acc*[n2] = W2aug . h1^T ----
        f32x4 accA[6], accB[6];
#pragma unroll
        for (int n2 = 0; n2 < 6; ++n2) {
            accA[n2] = (f32x4){0.f,0.f,0.f,0.f};
            accB[n2] = (f32x4){0.f,0.f,0.f,0.f};
        }
#pragma unroll
        for (int t4 = 0; t4 < 4; ++t4)
#pragma unroll
            for (int n2 = 0; n2 < 6; ++n2) {
                accA[n2] = __builtin_amdgcn_mfma_f32_16x16x32_f16(
                    w2f[n2*4 + t4], pbA[t4], accA[n2], 0, 0, 0);
                accB[n2] = __builtin_amdgcn_mfma_f32_16x16x32_f16(
                    w2f[n2*4 + t4], pbB[t4], accB[n2], 0, 0, 0);
            }

        // ---- pack h2 B-frags ----
        f16x8 phA[3], phB[3];
#pragma unroll
        for (int t3 = 0; t3 < 3; ++t3) {
#pragma unroll
            for (int j = 0; j < 4; ++j) {
                phA[t3][j]     = (_Float16)fmaxf(accA[2*t3][j],     0.f);
                phA[t3][j + 4] = (_Float16)fmaxf(accA[2*t3 + 1][j], 0.f);
                phB[t3][j]     = (_Float16)fmaxf(accB[2*t3][j],     0.f);
                phB[t3][j + 4] = (_Float16)fmaxf(accB[2*t3 + 1][j], 0.f);
            }
        }

        // ---- L3 ----
        f32x4 acyA = (f32x4){0.f,0.f,0.f,0.f};
        f32x4 acyB = (f32x4){0.f,0.f,0.f,0.f};
#pragma unroll
        for (int t3 = 0; t3 < 3; ++t3) {
            acyA = __builtin_amdgcn_mfma_f32_16x16x32_f16(w3f[t3], phA[t3], acyA, 0, 0, 0);
            acyB = __builtin_amdgcn_mfma_f32_16x16x32_f16(w3f[t3], phB[t3], acyB, 0, 0, 0);
        }

        // ---- epilogue (both tiles) ----
        float rA0 = fmaxf(acyA[0], 0.f);
        float rB0 = fmaxf(acyB[0], 0.f);
        float y4A = __shfl(rA0, c + 16, 64);   // out4 lives in q==1, j==0
        float y4B = __shfl(rB0, c + 16, 64);
        if (validA) {
            float y0 = rA0;
            float y1 = fmaxf(acyA[1], 0.f);
            float y2 = fmaxf(acyA[2], 0.f);
            float y3 = fmaxf(acyA[3], 0.f);
            float ss = y0*y0 + y1*y1 + y2*y2 + y3*y3 + y4A*y4A;
            float inv = 1.0f / fmaxf(sqrtf(ss), 1e-12f);
            float* op = out + rowA * 5;
            op[0] = (xA[0] != 0.f) ? 0.f : y0 * inv;
            op[1] = (xA[1] != 0.f) ? 0.f : y1 * inv;
            op[2] = (xA[2] != 0.f) ? 0.f : y2 * inv;
            op[3] = (xA[3] != 0.f) ? 0.f : y3 * inv;
            op[4] = (xA[4] != 0.f) ? 0.f : y4A * inv;
            if (ss < TAU2) {
                unsigned int idx = atomicAdd(cnt, 1u);
                if (idx < cap) list[idx] = (unsigned int)rowA;
            }
        }
        if (validB) {
            float y0 = rB0;
            float y1 = fmaxf(acyB[1], 0.f);
            float y2 = fmaxf(acyB[2], 0.f);
            float y3 = fmaxf(acyB[3], 0.f);
            float ss = y0*y0 + y1*y1 + y2*y2 + y3*y3 + y4B*y4B;
            float inv = 1.0f / fmaxf(sqrtf(ss), 1e-12f);
            float* op = out + rowB * 5;
            op[0] = (xB[0] != 0.f) ? 0.f : y0 * inv;
            op[1] = (xB[1] != 0.f) ? 0.f : y1 * inv;
            op[2] = (xB[2] != 0.f) ? 0.f : y2 * inv;
            op[3] = (xB[3] != 0.f) ? 0.f : y3 * inv;
            op[4] = (xB[4] != 0.f) ? 0.f : y4B * inv;
            if (ss < TAU2) {
                unsigned int idx = atomicAdd(cnt, 1u);
                if (idx < cap) list[idx] = (unsigned int)rowB;
            }
        }
    }
}

// ---------------- rescue (exact f32, R3 structure) ----------------
template <int G0>
__device__ __forceinline__ void half_pass(
    const float xv[5],
    const float* __restrict__ W1, const float* __restrict__ b1,
    const float* __restrict__ W2T, const float* __restrict__ b2,
    const float* __restrict__ W3,
    float y[5])
{
    float acc[42];
#pragma unroll
    for (int g = 0; g < 42; ++g) acc[g] = b2[G0 + g];
    for (int h = 0; h < 120; ++h) {
        float a = b1[h];
        a = fmaf(W1[h*5 + 0], xv[0], a);
        a = fmaf(W1[h*5 + 1], xv[1], a);
        a = fmaf(W1[h*5 + 2], xv[2], a);
        a = fmaf(W1[h*5 + 3], xv[3], a);
        a = fmaf(W1[h*5 + 4], xv[4], a);
        a = fmaxf(a, 0.0f);
        const float* wr = W2T + h*84 + G0;
#pragma unroll
        for (int g = 0; g < 42; ++g) acc[g] = fmaf(wr[g], a, acc[g]);
    }
#pragma unroll
    for (int g = 0; g < 42; ++g) acc[g] = fmaxf(acc[g], 0.0f);
#pragma unroll
    for (int o = 0; o < 5; ++o) {
        const float* w3o = W3 + o*84 + G0;
        float ty = y[o];
#pragma unroll
        for (int g = 0; g < 42; ++g) ty = fmaf(w3o[g], acc[g], ty);
        y[o] = ty;
    }
}

__global__ __launch_bounds__(256) void rescue_kernel(
    const float* __restrict__ x,
    const float* __restrict__ W1, const float* __restrict__ b1,
    const char*  __restrict__ ws, const float* __restrict__ b2,
    const float* __restrict__ W3, const float* __restrict__ b3,
    float* __restrict__ out, unsigned int cap, int nrows)
{
    const unsigned int* cnt  = (const unsigned int*)(ws + CNT_OFF);
    const unsigned int* list = (const unsigned int*)(ws + LIST_OFF);
    const float* W2T = (const float*)(ws + W2T_OFF);
    unsigned int count = *cnt;
    if (count > cap) count = cap;

    for (unsigned int t = blockIdx.x * 256 + threadIdx.x;
         t < count; t += gridDim.x * 256) {
        long row = (long)list[t];
        if (row < 0 || row >= (long)nrows) continue;   // replay-safety guard

        const float* xr = x + row * 5;
        float xv[5];
#pragma unroll
        for (int i = 0; i < 5; ++i) xv[i] = xr[i];

        float y[5];
#pragma unroll
        for (int o = 0; o < 5; ++o) y[o] = b3[o];
        half_pass<0>(xv, W1, b1, W2T, b2, W3, y);
        half_pass<42>(xv, W1, b1, W2T, b2, W3, y);
#pragma unroll
        for (int o = 0; o < 5; ++o) y[o] = fmaxf(y[o], 0.0f);

        float ss = y[0]*y[0];
        ss = fmaf(y[1], y[1], ss);
        ss = fmaf(y[2], y[2], ss);
        ss = fmaf(y[3], y[3], ss);
        ss = fmaf(y[4], y[4], ss);
        float inv = 1.0f / fmaxf(sqrtf(ss), 1e-12f);
        float* op = out + row * 5;
#pragma unroll
        for (int o = 0; o < 5; ++o)
            op[o] = (xv[o] != 0.f) ? 0.f : y[o] * inv;
    }
}

// ---------------- launch ----------------
extern "C" void kernel_launch(void* const* d_in, const int* in_sizes, int n_in,
                              void* d_out, int out_size, void* d_ws, size_t ws_size,
                              hipStream_t stream) {
    const float* x  = (const float*)d_in[0];
    const float* W1 = (const float*)d_in[1];
    const float* b1 = (const float*)d_in[2];
    const float* W2 = (const float*)d_in[3];
    const float* b2 = (const float*)d_in[4];
    const float* W3 = (const float*)d_in[5];
    const float* b3 = (const float*)d_in[6];
    float* out = (float*)d_out;
    char* ws = (char*)d_ws;

    const int nrows = in_sizes[0] / 5;
    const int ntiles = (nrows + 15) / 16;
    const int npairs = (ntiles + 1) / 2;
    unsigned int cap = (ws_size > (size_t)LIST_OFF + 4)
                       ? (unsigned int)((ws_size - LIST_OFF) / 4) : 0u;
    unsigned int* cnt  = (unsigned int*)(ws + CNT_OFF);
    unsigned int* list = (unsigned int*)(ws + LIST_OFF);

    pack_kernel<<<48, 256, 0, stream>>>(W1, b1, W2, b2, W3, b3, ws);

    mfma_main<<<512, 256, 0, stream>>>(x, ws, out, cnt, list, cap,
                                       nrows, npairs);

    rescue_kernel<<<256, 256, 0, stream>>>(x, W1, b1, ws, b2, W3, b3,
                                           out, cap, nrows);
}

// Round 13
// 79.642 us; speedup vs baseline: 3.9470x; 1.7672x over previous
//
#include <hip/hip_runtime.h>

// Per-row MLP 5->120->84->5 + relu + L2-normalize + x!=0 mask.
// R13 = R12 (2-tile-interleaved zero-LDS swapped-operand MFMA main) with the
// rescue kernel rewritten WAVE-PARALLEL: one wave per rescued row, lane g
// owns h2 outputs {g, g+64}; h1 values computed uniformly on the fly (never
// stored); y via 5 x shfl_xor tree reductions; lane 0 stores. Per-row chain
// ~200K cyc (serial-thread R12 rescue, measured 83 us @0.3% occupancy) ->
// ~5K cyc, spread over 1024 waves. W2T pack dropped (rescue reads W2 direct).

typedef _Float16 f16x8 __attribute__((ext_vector_type(8)));
typedef float    f32x4 __attribute__((ext_vector_type(4)));

#define CNT_OFF  0
#define W1A_OFF  40384       // f16[8][64][8]        -> ends 48576
#define W2A_OFF  48576       // f16[24][64][8]       -> ends 73152
#define W3A_OFF  73152       // f16[3][64][8]        -> ends 76224
#define LIST_OFF 76224
#define TAU2     0.04f       // rescue if ||y||^2 < 0.2^2

// ---------------- pack ----------------
__global__ __launch_bounds__(256) void pack_kernel(
    const float* __restrict__ W1, const float* __restrict__ b1,
    const float* __restrict__ W2, const float* __restrict__ b2,
    const float* __restrict__ W3, const float* __restrict__ b3,
    char* __restrict__ ws)
{
    int i = blockIdx.x * 256 + threadIdx.x;
    if (i == 0) *(unsigned int*)(ws + CNT_OFF) = 0u;
    _Float16* W1a = (_Float16*)(ws + W1A_OFF);
    _Float16* W2a = (_Float16*)(ws + W2A_OFF);
    _Float16* W3a = (_Float16*)(ws + W3A_OFF);

    // W1a[n][l][j]: A-frag of W1aug. feat = 16n + (l&15), k = (l>>4)*8 + j.
    if (i < 4096) {
        int n = i >> 9, l = (i >> 3) & 63, j = i & 7;
        int feat = 16*n + (l & 15);
        int k = (l >> 4) * 8 + j;
        float v = 0.f;
        if (feat < 120) {
            if (k < 5) v = W1[feat*5 + k];
            else if (k == 5) v = b1[feat];
        } else if (feat == 120 && k == 5) v = 1.f;
        W1a[i] = (_Float16)v;
    }
    // W2a[b=(n2*4+t4)][l][j']: A-frag of W2aug, k-permuted:
    //   f = 32*t4 + 16*(j'>>2) + 4*(l>>4) + (j'&3)
    if (i < 12288) {
        int b = i >> 9, l = (i >> 3) & 63, j = i & 7;
        int n2 = b >> 2, t4 = b & 3;
        int g = 16*n2 + (l & 15);
        int f = 32*t4 + 16*(j >> 2) + 4*(l >> 4) + (j & 3);
        float v = 0.f;
        if (g < 84) {
            if (f < 120) v = W2[g*120 + f];
            else if (f == 120) v = b2[g];
        } else if (g == 84 && f == 120) v = 1.f;
        W2a[i] = (_Float16)v;
    }
    // W3a[t3][l][j']: A-frag of W3aug, same k-permutation over h2 features.
    if (i < 1536) {
        int t3 = i >> 9, l = (i >> 3) & 63, j = i & 7;
        int o = l & 15;
        int f = 32*t3 + 16*(j >> 2) + 4*(l >> 4) + (j & 3);
        float v = 0.f;
        if (o < 5) {
            if (f < 84) v = W3[o*84 + f];
            else if (f == 84) v = b3[o];
        }
        W3a[i] = (_Float16)v;
    }
}

// ---------------- main (persistent, zero-LDS, 2-tile interleave) ----------
__global__ __launch_bounds__(256, 2) void mfma_main(
    const float* __restrict__ x, const char* __restrict__ ws,
    float* __restrict__ out,
    unsigned int* __restrict__ cnt, unsigned int* __restrict__ list,
    unsigned int cap, int nrows, int npairs)
{
    const _Float16* W1a = (const _Float16*)(ws + W1A_OFF);
    const _Float16* W2a = (const _Float16*)(ws + W2A_OFF);
    const _Float16* W3a = (const _Float16*)(ws + W3A_OFF);

    const int tid  = threadIdx.x;
    const int w    = tid >> 6, lane = tid & 63;
    const int c    = lane & 15, q = lane >> 4;

    // persistent weight fragments (loaded once per wave; live in VGPR/AGPR)
    f16x8 w1f[8], w2f[24], w3f[3];
#pragma unroll
    for (int n = 0; n < 8; ++n)  w1f[n] = *(const f16x8*)(W1a + (n*64 + lane)*8);
#pragma unroll
    for (int b = 0; b < 24; ++b) w2f[b] = *(const f16x8*)(W2a + (b*64 + lane)*8);
#pragma unroll
    for (int t = 0; t < 3; ++t)  w3f[t] = *(const f16x8*)(W3a + (t*64 + lane)*8);

    const int gw = blockIdx.x * 4 + w;
    const int nw = gridDim.x * 4;

    // prefetch x for the first pair (tiles 2p and 2p+1 -> rows 32p+c, +16)
    float nxA[5] = {0.f, 0.f, 0.f, 0.f, 0.f};
    float nxB[5] = {0.f, 0.f, 0.f, 0.f, 0.f};
    if (q == 0 && gw < npairs) {
        long rA = (long)gw * 32 + c;
        long rB = rA + 16;
        if (rA < nrows) {
            const float* xp = x + rA * 5;
            nxA[0]=xp[0]; nxA[1]=xp[1]; nxA[2]=xp[2]; nxA[3]=xp[3]; nxA[4]=xp[4];
        }
        if (rB < nrows) {
            const float* xp = x + rB * 5;
            nxB[0]=xp[0]; nxB[1]=xp[1]; nxB[2]=xp[2]; nxB[3]=xp[3]; nxB[4]=xp[4];
        }
    }

    for (int p = gw; p < npairs; p += nw) {
        const long rowA = (long)p * 32 + c;
        const long rowB = rowA + 16;
        const bool validA = (q == 0) && (rowA < nrows);
        const bool validB = (q == 0) && (rowB < nrows);

        // consume prefetched x
        float xA[5], xB[5];
#pragma unroll
        for (int i = 0; i < 5; ++i) { xA[i] = nxA[i]; xB[i] = nxB[i]; }

        // issue next pair's loads now (hidden under this pair's compute)
#pragma unroll
        for (int i = 0; i < 5; ++i) { nxA[i] = 0.f; nxB[i] = 0.f; }
        {
            const int pn = p + nw;
            if (q == 0 && pn < npairs) {
                long rA = (long)pn * 32 + c;
                long rB = rA + 16;
                if (rA < nrows) {
                    const float* xp = x + rA * 5;
                    nxA[0]=xp[0]; nxA[1]=xp[1]; nxA[2]=xp[2]; nxA[3]=xp[3]; nxA[4]=xp[4];
                }
                if (rB < nrows) {
                    const float* xp = x + rB * 5;
                    nxB[0]=xp[0]; nxB[1]=xp[1]; nxB[2]=xp[2]; nxB[3]=xp[3]; nxB[4]=xp[4];
                }
            }
        }

        // B-frags of xaug^T
        f16x8 axA, axB;
#pragma unroll
        for (int j = 0; j < 8; ++j) { axA[j] = (_Float16)0.f; axB[j] = (_Float16)0.f; }
        if (validA) {
            axA[0]=(_Float16)xA[0]; axA[1]=(_Float16)xA[1]; axA[2]=(_Float16)xA[2];
            axA[3]=(_Float16)xA[3]; axA[4]=(_Float16)xA[4]; axA[5]=(_Float16)1.f;
        }
        if (validB) {
            axB[0]=(_Float16)xB[0]; axB[1]=(_Float16)xB[1]; axB[2]=(_Float16)xB[2];
            axB[3]=(_Float16)xB[3]; axB[4]=(_Float16)xB[4]; axB[5]=(_Float16)1.f;
        }

        // ---- L1 + fused h1-pack: pb*[t4] B-frags (k-order = W2a's perm) ----
        f16x8 pbA[4], pbB[4];
#pragma unroll
        for (int t4 = 0; t4 < 4; ++t4) {
            f32x4 dA0 = __builtin_amdgcn_mfma_f32_16x16x32_f16(
                w1f[2*t4],     axA, (f32x4){0.f,0.f,0.f,0.f}, 0, 0, 0);
            f32x4 dB0 = __builtin_amdgcn_mfma_f32_16x16x32_f16(
                w1f[2*t4],     axB, (f32x4){0.f,0.f,0.f,0.f}, 0, 0, 0);
            f32x4 dA1 = __builtin_amdgcn_mfma_f32_16x16x32_f16(
                w1f[2*t4 + 1], axA, (f32x4){0.f,0.f,0.f,0.f}, 0, 0, 0);
            f32x4 dB1 = __builtin_amdgcn_mfma_f32_16x16x32_f16(
                w1f[2*t4 + 1], axB, (f32x4){0.f,0.f,0.f,0.f}, 0, 0, 0);
#pragma unroll
            for (int j = 0; j < 4; ++j) {
                pbA[t4][j]     = (_Float16)fmaxf(dA0[j], 0.f);
                pbA[t4][j + 4] = (_Float16)fmaxf(dA1[j], 0.f);
                pbB[t4][j]     = (_Float16)fmaxf(dB0[j], 0.f);
                pbB[t4][j + 4] = (_Float16)fmaxf(dB1[j], 0.f);
            }
        }

        // ---- L2: acc*[n2] = W2aug . h1^T ----
        f32x4 accA[6], accB[6];
#pragma unroll
        for (int n2 = 0; n2 < 6; ++n2) {
            accA[n2] = (f32x4){0.f,0.f,0.f,0.f};
            accB[n2] = (f32x4){0.f,0.f,0.f,0.f};
        }
#pragma unroll
        for (int t4 = 0; t4 < 4; ++t4)
#pragma unroll
            for (int n2 = 0; n2 < 6; ++n2) {
                accA[n2] = __builtin_amdgcn_mfma_f32_16x16x32_f16(
                    w2f[n2*4 + t4], pbA[t4], accA[n2], 0, 0, 0);
                accB[n2] = __builtin_amdgcn_mfma_f32_16x16x32_f16(
                    w2f[n2*4 + t4], pbB[t4], accB[n2], 0, 0, 0);
            }

        // ---- pack h2 B-frags ----
        f16x8 phA[3], phB[3];
#pragma unroll
        for (int t3 = 0; t3 < 3; ++t3) {
#pragma unroll
            for (int j = 0; j < 4; ++j) {
                phA[t3][j]     = (_Float16)fmaxf(accA[2*t3][j],     0.f);
                phA[t3][j + 4] = (_Float16)fmaxf(accA[2*t3 + 1][j], 0.f);
                phB[t3][j]     = (_Float16)fmaxf(accB[2*t3][j],     0.f);
                phB[t3][j + 4] = (_Float16)fmaxf(accB[2*t3 + 1][j], 0.f);
            }
        }

        // ---- L3 ----
        f32x4 acyA = (f32x4){0.f,0.f,0.f,0.f};
        f32x4 acyB = (f32x4){0.f,0.f,0.f,0.f};
#pragma unroll
        for (int t3 = 0; t3 < 3; ++t3) {
            acyA = __builtin_amdgcn_mfma_f32_16x16x32_f16(w3f[t3], phA[t3], acyA, 0, 0, 0);
            acyB = __builtin_amdgcn_mfma_f32_16x16x32_f16(w3f[t3], phB[t3], acyB, 0, 0, 0);
        }

        // ---- epilogue (both tiles) ----
        float rA0 = fmaxf(acyA[0], 0.f);
        float rB0 = fmaxf(acyB[0], 0.f);
        float y4A = __shfl(rA0, c + 16, 64);   // out4 lives in q==1, j==0
        float y4B = __shfl(rB0, c + 16, 64);
        if (validA) {
            float y0 = rA0;
            float y1 = fmaxf(acyA[1], 0.f);
            float y2 = fmaxf(acyA[2], 0.f);
            float y3 = fmaxf(acyA[3], 0.f);
            float ss = y0*y0 + y1*y1 + y2*y2 + y3*y3 + y4A*y4A;
            float inv = 1.0f / fmaxf(sqrtf(ss), 1e-12f);
            float* op = out + rowA * 5;
            op[0] = (xA[0] != 0.f) ? 0.f : y0 * inv;
            op[1] = (xA[1] != 0.f) ? 0.f : y1 * inv;
            op[2] = (xA[2] != 0.f) ? 0.f : y2 * inv;
            op[3] = (xA[3] != 0.f) ? 0.f : y3 * inv;
            op[4] = (xA[4] != 0.f) ? 0.f : y4A * inv;
            if (ss < TAU2) {
                unsigned int idx = atomicAdd(cnt, 1u);
                if (idx < cap) list[idx] = (unsigned int)rowA;
            }
        }
        if (validB) {
            float y0 = rB0;
            float y1 = fmaxf(acyB[1], 0.f);
            float y2 = fmaxf(acyB[2], 0.f);
            float y3 = fmaxf(acyB[3], 0.f);
            float ss = y0*y0 + y1*y1 + y2*y2 + y3*y3 + y4B*y4B;
            float inv = 1.0f / fmaxf(sqrtf(ss), 1e-12f);
            float* op = out + rowB * 5;
            op[0] = (xB[0] != 0.f) ? 0.f : y0 * inv;
            op[1] = (xB[1] != 0.f) ? 0.f : y1 * inv;
            op[2] = (xB[2] != 0.f) ? 0.f : y2 * inv;
            op[3] = (xB[3] != 0.f) ? 0.f : y3 * inv;
            op[4] = (xB[4] != 0.f) ? 0.f : y4B * inv;
            if (ss < TAU2) {
                unsigned int idx = atomicAdd(cnt, 1u);
                if (idx < cap) list[idx] = (unsigned int)rowB;
            }
        }
    }
}

// ---------------- rescue (exact f32, WAVE-parallel: 1 wave per row) -------
__global__ __launch_bounds__(256) void rescue_kernel(
    const float* __restrict__ x,
    const float* __restrict__ W1, const float* __restrict__ b1,
    const float* __restrict__ W2, const float* __restrict__ b2,
    const float* __restrict__ W3, const float* __restrict__ b3,
    const char* __restrict__ ws, float* __restrict__ out,
    unsigned int cap, int nrows)
{
    const unsigned int* cnt  = (const unsigned int*)(ws + CNT_OFF);
    const unsigned int* list = (const unsigned int*)(ws + LIST_OFF);
    unsigned int count = *cnt;
    if (count > cap) count = cap;

    const int lane   = threadIdx.x & 63;
    const int wid    = (blockIdx.x * 256 + threadIdx.x) >> 6;
    const int nwaves = (gridDim.x * 256) >> 6;

    const int g1 = lane;                        // h2 output 0..63
    const bool has2 = (lane < 20);
    const int g2 = has2 ? (64 + lane) : 0;      // h2 output 64..83 (clamped)

    for (unsigned int t = wid; t < count; t += nwaves) {
        long row = (long)list[t];
        if (row < 0 || row >= (long)nrows) continue;   // replay-safety guard

        const float* xr = x + row * 5;                 // uniform across wave
        const float xv0 = xr[0], xv1 = xr[1], xv2 = xr[2],
                    xv3 = xr[3], xv4 = xr[4];

        // h2[g] = relu(b2[g] + sum_h W2[g][h] * relu(W1[h].x + b1[h]))
        float acc1 = b2[g1];
        float acc2 = has2 ? b2[g2] : 0.f;
        const float* w2r1 = W2 + (size_t)g1 * 120;
        const float* w2r2 = W2 + (size_t)g2 * 120;
        for (int h = 0; h < 120; ++h) {
            float a = b1[h];
            a = fmaf(W1[h*5 + 0], xv0, a);
            a = fmaf(W1[h*5 + 1], xv1, a);
            a = fmaf(W1[h*5 + 2], xv2, a);
            a = fmaf(W1[h*5 + 3], xv3, a);
            a = fmaf(W1[h*5 + 4], xv4, a);
            a = fmaxf(a, 0.0f);                        // h1[h], uniform
            acc1 = fmaf(w2r1[h], a, acc1);
            acc2 = fmaf(w2r2[h], a, acc2);             // branch-free (clamped)
        }
        float h2a = fmaxf(acc1, 0.f);
        float h2b = has2 ? fmaxf(acc2, 0.f) : 0.f;

        // y[o] = relu(b3[o] + sum_g W3[o][g] * h2[g]) via wave reduction
        float y[5];
#pragma unroll
        for (int o = 0; o < 5; ++o) {
            float p = W3[o*84 + g1] * h2a;
            if (has2) p = fmaf(W3[o*84 + g2], h2b, p);
#pragma unroll
            for (int s = 1; s < 64; s <<= 1) p += __shfl_xor(p, s, 64);
            y[o] = fmaxf(p + b3[o], 0.f);
        }

        if (lane == 0) {
            float ss = y[0]*y[0];
            ss = fmaf(y[1], y[1], ss);
            ss = fmaf(y[2], y[2], ss);
            ss = fmaf(y[3], y[3], ss);
            ss = fmaf(y[4], y[4], ss);
            float inv = 1.0f / fmaxf(sqrtf(ss), 1e-12f);
            float* op = out + row * 5;
#pragma unroll
            for (int o = 0; o < 5; ++o)
                op[o] = (xr[o] != 0.f) ? 0.f : y[o] * inv;
        }
    }
}

// ---------------- launch ----------------
extern "C" void kernel_launch(void* const* d_in, const int* in_sizes, int n_in,
                              void* d_out, int out_size, void* d_ws, size_t ws_size,
                              hipStream_t stream) {
    const float* x  = (const float*)d_in[0];
    const float* W1 = (const float*)d_in[1];
    const float* b1 = (const float*)d_in[2];
    const float* W2 = (const float*)d_in[3];
    const float* b2 = (const float*)d_in[4];
    const float* W3 = (const float*)d_in[5];
    const float* b3 = (const float*)d_in[6];
    float* out = (float*)d_out;
    char* ws = (char*)d_ws;

    const int nrows = in_sizes[0] / 5;
    const int ntiles = (nrows + 15) / 16;
    const int npairs = (ntiles + 1) / 2;
    unsigned int cap = (ws_size > (size_t)LIST_OFF + 4)
                       ? (unsigned int)((ws_size - LIST_OFF) / 4) : 0u;
    unsigned int* cnt  = (unsigned int*)(ws + CNT_OFF);
    unsigned int* list = (unsigned int*)(ws + LIST_OFF);

    pack_kernel<<<48, 256, 0, stream>>>(W1, b1, W2, b2, W3, b3, ws);

    mfma_main<<<512, 256, 0, stream>>>(x, ws, out, cnt, list, cap,
                                       nrows, npairs);

    rescue_kernel<<<256, 256, 0, stream>>>(x, W1, b1, W2, b2, W3, b3,
                                           ws, out, cap, nrows);
}

// Round 15
// 77.234 us; speedup vs baseline: 4.0700x; 1.0312x over previous
//
#include <hip/hip_runtime.h>

// Per-row MLP 5->120->84->5 + relu + L2-normalize + x!=0 mask.
// R15 = R14 with the cvt_pkrtz type mismatch fixed: the builtin returns
// __fp16x2, not _Float16x2 -- union member is now __fp16-typed and the
// result is bit-reinterpreted into the _Float16 vectors MFMA wants.
//  1. L1 on mfma_f32_16x16x16f16 (K=16): xaug uses K=6; halves L1 matrix
//     work and w1f regs (32->16). D layout identical (feat=16n+4q+j).
//  2. Packed f16 cvt via cvt_pkrtz (12 ops per f16x8 instead of 16).

typedef _Float16 f16x8 __attribute__((ext_vector_type(8)));
typedef _Float16 f16x4 __attribute__((ext_vector_type(4)));
typedef __fp16   hf16x2 __attribute__((ext_vector_type(2)));
typedef float    f32x4 __attribute__((ext_vector_type(4)));

#if __has_builtin(__builtin_amdgcn_mfma_f32_16x16x16f16)
#define HAVE_K16 1
#define MFMA16(a, b, c) __builtin_amdgcn_mfma_f32_16x16x16f16((a), (b), (c), 0, 0, 0)
#elif __has_builtin(__builtin_amdgcn_mfma_f32_16x16x16_f16)
#define HAVE_K16 1
#define MFMA16(a, b, c) __builtin_amdgcn_mfma_f32_16x16x16_f16((a), (b), (c), 0, 0, 0)
#else
#define HAVE_K16 0
#endif
#define MFMA32(a, b, c) __builtin_amdgcn_mfma_f32_16x16x32_f16((a), (b), (c), 0, 0, 0)

#define CNT_OFF  0
#define W1A_OFF  40384       // K16: f16[8][64][4]; K32: f16[8][64][8]
#define W2A_OFF  48576       // f16[24][64][8]       -> ends 73152
#define W3A_OFF  73152       // f16[3][64][8]        -> ends 76224
#define LIST_OFF 76224
#define TAU2     0.04f       // rescue if ||y||^2 < 0.2^2

__device__ __forceinline__ f16x8 pack_relu8(f32x4 d0, f32x4 d1) {
    union { f16x8 v; hf16x2 h[4]; } u;
    u.h[0] = __builtin_amdgcn_cvt_pkrtz(fmaxf(d0[0], 0.f), fmaxf(d0[1], 0.f));
    u.h[1] = __builtin_amdgcn_cvt_pkrtz(fmaxf(d0[2], 0.f), fmaxf(d0[3], 0.f));
    u.h[2] = __builtin_amdgcn_cvt_pkrtz(fmaxf(d1[0], 0.f), fmaxf(d1[1], 0.f));
    u.h[3] = __builtin_amdgcn_cvt_pkrtz(fmaxf(d1[2], 0.f), fmaxf(d1[3], 0.f));
    return u.v;
}

// ---------------- pack ----------------
__global__ __launch_bounds__(256) void pack_kernel(
    const float* __restrict__ W1, const float* __restrict__ b1,
    const float* __restrict__ W2, const float* __restrict__ b2,
    const float* __restrict__ W3, const float* __restrict__ b3,
    char* __restrict__ ws)
{
    int i = blockIdx.x * 256 + threadIdx.x;
    if (i == 0) *(unsigned int*)(ws + CNT_OFF) = 0u;
    _Float16* W1a = (_Float16*)(ws + W1A_OFF);
    _Float16* W2a = (_Float16*)(ws + W2A_OFF);
    _Float16* W3a = (_Float16*)(ws + W3A_OFF);

#if HAVE_K16
    // W1a[n][l][j]: K16 A-frag. feat = 16n + (l&15), k = (l>>4)*4 + j.
    if (i < 2048) {
        int n = i >> 8, l = (i >> 2) & 63, j = i & 3;
        int feat = 16*n + (l & 15);
        int k = (l >> 4) * 4 + j;
        float v = 0.f;
        if (feat < 120) {
            if (k < 5) v = W1[feat*5 + k];
            else if (k == 5) v = b1[feat];
        } else if (feat == 120 && k == 5) v = 1.f;
        W1a[i] = (_Float16)v;
    }
#else
    // W1a[n][l][j]: K32 A-frag. feat = 16n + (l&15), k = (l>>4)*8 + j.
    if (i < 4096) {
        int n = i >> 9, l = (i >> 3) & 63, j = i & 7;
        int feat = 16*n + (l & 15);
        int k = (l >> 4) * 8 + j;
        float v = 0.f;
        if (feat < 120) {
            if (k < 5) v = W1[feat*5 + k];
            else if (k == 5) v = b1[feat];
        } else if (feat == 120 && k == 5) v = 1.f;
        W1a[i] = (_Float16)v;
    }
#endif
    // W2a[b=(n2*4+t4)][l][j']: A-frag of W2aug, k-permuted:
    //   f = 32*t4 + 16*(j'>>2) + 4*(l>>4) + (j'&3)
    if (i < 12288) {
        int b = i >> 9, l = (i >> 3) & 63, j = i & 7;
        int n2 = b >> 2, t4 = b & 3;
        int g = 16*n2 + (l & 15);
        int f = 32*t4 + 16*(j >> 2) + 4*(l >> 4) + (j & 3);
        float v = 0.f;
        if (g < 84) {
            if (f < 120) v = W2[g*120 + f];
            else if (f == 120) v = b2[g];
        } else if (g == 84 && f == 120) v = 1.f;
        W2a[i] = (_Float16)v;
    }
    // W3a[t3][l][j']: same k-permutation over h2 features.
    if (i < 1536) {
        int t3 = i >> 9, l = (i >> 3) & 63, j = i & 7;
        int o = l & 15;
        int f = 32*t3 + 16*(j >> 2) + 4*(l >> 4) + (j & 3);
        float v = 0.f;
        if (o < 5) {
            if (f < 84) v = W3[o*84 + f];
            else if (f == 84) v = b3[o];
        }
        W3a[i] = (_Float16)v;
    }
}

// ---------------- main (persistent, zero-LDS, 2-tile interleave) ----------
__global__ __launch_bounds__(256, 2) void mfma_main(
    const float* __restrict__ x, const char* __restrict__ ws,
    float* __restrict__ out,
    unsigned int* __restrict__ cnt, unsigned int* __restrict__ list,
    unsigned int cap, int nrows, int npairs)
{
    const _Float16* W1a = (const _Float16*)(ws + W1A_OFF);
    const _Float16* W2a = (const _Float16*)(ws + W2A_OFF);
    const _Float16* W3a = (const _Float16*)(ws + W3A_OFF);

    const int tid  = threadIdx.x;
    const int w    = tid >> 6, lane = tid & 63;
    const int c    = lane & 15, q = lane >> 4;

    // persistent weight fragments (loaded once per wave)
#if HAVE_K16
    f16x4 w1f[8];
#pragma unroll
    for (int n = 0; n < 8; ++n)  w1f[n] = *(const f16x4*)(W1a + (n*64 + lane)*4);
#else
    f16x8 w1f[8];
#pragma unroll
    for (int n = 0; n < 8; ++n)  w1f[n] = *(const f16x8*)(W1a + (n*64 + lane)*8);
#endif
    f16x8 w2f[24], w3f[3];
#pragma unroll
    for (int b = 0; b < 24; ++b) w2f[b] = *(const f16x8*)(W2a + (b*64 + lane)*8);
#pragma unroll
    for (int t = 0; t < 3; ++t)  w3f[t] = *(const f16x8*)(W3a + (t*64 + lane)*8);

    const int gw = blockIdx.x * 4 + w;
    const int nw = gridDim.x * 4;

    // prefetch x for the first pair (tiles 2p and 2p+1 -> rows 32p+c, +16)
    float nxA[5] = {0.f, 0.f, 0.f, 0.f, 0.f};
    float nxB[5] = {0.f, 0.f, 0.f, 0.f, 0.f};
    if (q == 0 && gw < npairs) {
        long rA = (long)gw * 32 + c;
        long rB = rA + 16;
        if (rA < nrows) {
            const float* xp = x + rA * 5;
            nxA[0]=xp[0]; nxA[1]=xp[1]; nxA[2]=xp[2]; nxA[3]=xp[3]; nxA[4]=xp[4];
        }
        if (rB < nrows) {
            const float* xp = x + rB * 5;
            nxB[0]=xp[0]; nxB[1]=xp[1]; nxB[2]=xp[2]; nxB[3]=xp[3]; nxB[4]=xp[4];
        }
    }

    for (int p = gw; p < npairs; p += nw) {
        const long rowA = (long)p * 32 + c;
        const long rowB = rowA + 16;
        const bool validA = (q == 0) && (rowA < nrows);
        const bool validB = (q == 0) && (rowB < nrows);

        // consume prefetched x
        float xA[5], xB[5];
#pragma unroll
        for (int i = 0; i < 5; ++i) { xA[i] = nxA[i]; xB[i] = nxB[i]; }

        // issue next pair's loads now (hidden under this pair's compute)
#pragma unroll
        for (int i = 0; i < 5; ++i) { nxA[i] = 0.f; nxB[i] = 0.f; }
        {
            const int pn = p + nw;
            if (q == 0 && pn < npairs) {
                long rA = (long)pn * 32 + c;
                long rB = rA + 16;
                if (rA < nrows) {
                    const float* xp = x + rA * 5;
                    nxA[0]=xp[0]; nxA[1]=xp[1]; nxA[2]=xp[2]; nxA[3]=xp[3]; nxA[4]=xp[4];
                }
                if (rB < nrows) {
                    const float* xp = x + rB * 5;
                    nxB[0]=xp[0]; nxB[1]=xp[1]; nxB[2]=xp[2]; nxB[3]=xp[3]; nxB[4]=xp[4];
                }
            }
        }

#if HAVE_K16
        // K16 B-frag: lane holds xaug[c][k=q*4+j].
        // q==0: [x0,x1,x2,x3]; q==1: [x4, 1, 0, 0]; else 0. (Invalid rows
        // compute bias-only garbage, discarded by the epilogue guard.)
        const float x4A = __shfl(xA[4], c, 64);   // broadcast q0's x4 to all q
        const float x4B = __shfl(xB[4], c, 64);
        f16x4 axA, axB;
        {
            union { f16x4 v; hf16x2 h[2]; } ua, ub;
            float aA0 = (q == 0) ? xA[0] : ((q == 1) ? x4A : 0.f);
            float aA1 = (q == 0) ? xA[1] : ((q == 1) ? 1.f  : 0.f);
            float aA2 = (q == 0) ? xA[2] : 0.f;
            float aA3 = (q == 0) ? xA[3] : 0.f;
            float aB0 = (q == 0) ? xB[0] : ((q == 1) ? x4B : 0.f);
            float aB1 = (q == 0) ? xB[1] : ((q == 1) ? 1.f  : 0.f);
            float aB2 = (q == 0) ? xB[2] : 0.f;
            float aB3 = (q == 0) ? xB[3] : 0.f;
            ua.h[0] = __builtin_amdgcn_cvt_pkrtz(aA0, aA1);
            ua.h[1] = __builtin_amdgcn_cvt_pkrtz(aA2, aA3);
            ub.h[0] = __builtin_amdgcn_cvt_pkrtz(aB0, aB1);
            ub.h[1] = __builtin_amdgcn_cvt_pkrtz(aB2, aB3);
            axA = ua.v; axB = ub.v;
        }
#else
        // K32 B-frag: lane holds xaug[c][k=q*8+j]; q==0: [x0..x4,1,0,0]
        f16x8 axA, axB;
#pragma unroll
        for (int j = 0; j < 8; ++j) { axA[j] = (_Float16)0.f; axB[j] = (_Float16)0.f; }
        if (validA) {
            axA[0]=(_Float16)xA[0]; axA[1]=(_Float16)xA[1]; axA[2]=(_Float16)xA[2];
            axA[3]=(_Float16)xA[3]; axA[4]=(_Float16)xA[4]; axA[5]=(_Float16)1.f;
        }
        if (validB) {
            axB[0]=(_Float16)xB[0]; axB[1]=(_Float16)xB[1]; axB[2]=(_Float16)xB[2];
            axB[3]=(_Float16)xB[3]; axB[4]=(_Float16)xB[4]; axB[5]=(_Float16)1.f;
        }
#endif

        // ---- L1 + fused h1-pack: pb*[t4] (feat = 16n + 4q + j) ----
        f16x8 pbA[4], pbB[4];
#pragma unroll
        for (int t4 = 0; t4 < 4; ++t4) {
#if HAVE_K16
            f32x4 dA0 = MFMA16(w1f[2*t4],     axA, ((f32x4){0.f,0.f,0.f,0.f}));
            f32x4 dB0 = MFMA16(w1f[2*t4],     axB, ((f32x4){0.f,0.f,0.f,0.f}));
            f32x4 dA1 = MFMA16(w1f[2*t4 + 1], axA, ((f32x4){0.f,0.f,0.f,0.f}));
            f32x4 dB1 = MFMA16(w1f[2*t4 + 1], axB, ((f32x4){0.f,0.f,0.f,0.f}));
#else
            f32x4 dA0 = MFMA32(w1f[2*t4],     axA, ((f32x4){0.f,0.f,0.f,0.f}));
            f32x4 dB0 = MFMA32(w1f[2*t4],     axB, ((f32x4){0.f,0.f,0.f,0.f}));
            f32x4 dA1 = MFMA32(w1f[2*t4 + 1], axA, ((f32x4){0.f,0.f,0.f,0.f}));
            f32x4 dB1 = MFMA32(w1f[2*t4 + 1], axB, ((f32x4){0.f,0.f,0.f,0.f}));
#endif
            pbA[t4] = pack_relu8(dA0, dA1);
            pbB[t4] = pack_relu8(dB0, dB1);
        }

        // ---- L2: acc*[n2] = W2aug . h1^T ----
        f32x4 accA[6], accB[6];
#pragma unroll
        for (int n2 = 0; n2 < 6; ++n2) {
            accA[n2] = (f32x4){0.f,0.f,0.f,0.f};
            accB[n2] = (f32x4){0.f,0.f,0.f,0.f};
        }
#pragma unroll
        for (int t4 = 0; t4 < 4; ++t4)
#pragma unroll
            for (int n2 = 0; n2 < 6; ++n2) {
                accA[n2] = MFMA32(w2f[n2*4 + t4], pbA[t4], accA[n2]);
                accB[n2] = MFMA32(w2f[n2*4 + t4], pbB[t4], accB[n2]);
            }

        // ---- pack h2 B-frags ----
        f16x8 phA[3], phB[3];
#pragma unroll
        for (int t3 = 0; t3 < 3; ++t3) {
            phA[t3] = pack_relu8(accA[2*t3], accA[2*t3 + 1]);
            phB[t3] = pack_relu8(accB[2*t3], accB[2*t3 + 1]);
        }

        // ---- L3 ----
        f32x4 acyA = (f32x4){0.f,0.f,0.f,0.f};
        f32x4 acyB = (f32x4){0.f,0.f,0.f,0.f};
#pragma unroll
        for (int t3 = 0; t3 < 3; ++t3) {
            acyA = MFMA32(w3f[t3], phA[t3], acyA);
            acyB = MFMA32(w3f[t3], phB[t3], acyB);
        }

        // ---- epilogue (both tiles) ----
        float rA0 = fmaxf(acyA[0], 0.f);
        float rB0 = fmaxf(acyB[0], 0.f);
        float y4A = __shfl(rA0, c + 16, 64);   // out4 lives in q==1, j==0
        float y4B = __shfl(rB0, c + 16, 64);
        if (validA) {
            float y0 = rA0;
            float y1 = fmaxf(acyA[1], 0.f);
            float y2 = fmaxf(acyA[2], 0.f);
            float y3 = fmaxf(acyA[3], 0.f);
            float ss = y0*y0 + y1*y1 + y2*y2 + y3*y3 + y4A*y4A;
            float inv = 1.0f / fmaxf(sqrtf(ss), 1e-12f);
            float* op = out + rowA * 5;
            op[0] = (xA[0] != 0.f) ? 0.f : y0 * inv;
            op[1] = (xA[1] != 0.f) ? 0.f : y1 * inv;
            op[2] = (xA[2] != 0.f) ? 0.f : y2 * inv;
            op[3] = (xA[3] != 0.f) ? 0.f : y3 * inv;
            op[4] = (xA[4] != 0.f) ? 0.f : y4A * inv;
            if (ss < TAU2) {
                unsigned int idx = atomicAdd(cnt, 1u);
                if (idx < cap) list[idx] = (unsigned int)rowA;
            }
        }
        if (validB) {
            float y0 = rB0;
            float y1 = fmaxf(acyB[1], 0.f);
            float y2 = fmaxf(acyB[2], 0.f);
            float y3 = fmaxf(acyB[3], 0.f);
            float ss = y0*y0 + y1*y1 + y2*y2 + y3*y3 + y4B*y4B;
            float inv = 1.0f / fmaxf(sqrtf(ss), 1e-12f);
            float* op = out + rowB * 5;
            op[0] = (xB[0] != 0.f) ? 0.f : y0 * inv;
            op[1] = (xB[1] != 0.f) ? 0.f : y1 * inv;
            op[2] = (xB[2] != 0.f) ? 0.f : y2 * inv;
            op[3] = (xB[3] != 0.f) ? 0.f : y3 * inv;
            op[4] = (xB[4] != 0.f) ? 0.f : y4B * inv;
            if (ss < TAU2) {
                unsigned int idx = atomicAdd(cnt, 1u);
                if (idx < cap) list[idx] = (unsigned int)rowB;
            }
        }
    }
}

// ---------------- rescue (exact f32, WAVE-parallel: 1 wave per row) -------
__global__ __launch_bounds__(256) void rescue_kernel(
    const float* __restrict__ x,
    const float* __restrict__ W1, const float* __restrict__ b1,
    const float* __restrict__ W2, const float* __restrict__ b2,
    const float* __restrict__ W3, const float* __restrict__ b3,
    const char* __restrict__ ws, float* __restrict__ out,
    unsigned int cap, int nrows)
{
    const unsigned int* cnt  = (const unsigned int*)(ws + CNT_OFF);
    const unsigned int* list = (const unsigned int*)(ws + LIST_OFF);
    unsigned int count = *cnt;
    if (count > cap) count = cap;

    const int lane   = threadIdx.x & 63;
    const int wid    = (blockIdx.x * 256 + threadIdx.x) >> 6;
    const int nwaves = (gridDim.x * 256) >> 6;

    const int g1 = lane;                        // h2 output 0..63
    const bool has2 = (lane < 20);
    const int g2 = has2 ? (64 + lane) : 0;      // h2 output 64..83 (clamped)

    for (unsigned int t = wid; t < count; t += nwaves) {
        long row = (long)list[t];
        if (row < 0 || row >= (long)nrows) continue;   // replay-safety guard

        const float* xr = x + row * 5;                 // uniform across wave
        const float xv0 = xr[0], xv1 = xr[1], xv2 = xr[2],
                    xv3 = xr[3], xv4 = xr[4];

        // h2[g] = relu(b2[g] + sum_h W2[g][h] * relu(W1[h].x + b1[h]))
        float acc1 = b2[g1];
        float acc2 = has2 ? b2[g2] : 0.f;
        const float* w2r1 = W2 + (size_t)g1 * 120;
        const float* w2r2 = W2 + (size_t)g2 * 120;
        for (int h = 0; h < 120; ++h) {
            float a = b1[h];
            a = fmaf(W1[h*5 + 0], xv0, a);
            a = fmaf(W1[h*5 + 1], xv1, a);
            a = fmaf(W1[h*5 + 2], xv2, a);
            a = fmaf(W1[h*5 + 3], xv3, a);
            a = fmaf(W1[h*5 + 4], xv4, a);
            a = fmaxf(a, 0.0f);                        // h1[h], uniform
            acc1 = fmaf(w2r1[h], a, acc1);
            acc2 = fmaf(w2r2[h], a, acc2);             // branch-free (clamped)
        }
        float h2a = fmaxf(acc1, 0.f);
        float h2b = has2 ? fmaxf(acc2, 0.f) : 0.f;

        // y[o] = relu(b3[o] + sum_g W3[o][g] * h2[g]) via wave reduction
        float y[5];
#pragma unroll
        for (int o = 0; o < 5; ++o) {
            float p = W3[o*84 + g1] * h2a;
            if (has2) p = fmaf(W3[o*84 + g2], h2b, p);
#pragma unroll
            for (int s = 1; s < 64; s <<= 1) p += __shfl_xor(p, s, 64);
            y[o] = fmaxf(p + b3[o], 0.f);
        }

        if (lane == 0) {
            float ss = y[0]*y[0];
            ss = fmaf(y[1], y[1], ss);
            ss = fmaf(y[2], y[2], ss);
            ss = fmaf(y[3], y[3], ss);
            ss = fmaf(y[4], y[4], ss);
            float inv = 1.0f / fmaxf(sqrtf(ss), 1e-12f);
            float* op = out + row * 5;
#pragma unroll
            for (int o = 0; o < 5; ++o)
                op[o] = (xr[o] != 0.f) ? 0.f : y[o] * inv;
        }
    }
}

// ---------------- launch ----------------
extern "C" void kernel_launch(void* const* d_in, const int* in_sizes, int n_in,
                              void* d_out, int out_size, void* d_ws, size_t ws_size,
                              hipStream_t stream) {
    const float* x  = (const float*)d_in[0];
    const float* W1 = (const float*)d_in[1];
    const float* b1 = (const float*)d_in[2];
    const float* W2 = (const float*)d_in[3];
    const float* b2 = (const float*)d_in[4];
    const float* W3 = (const float*)d_in[5];
    const float* b3 = (const float*)d_in[6];
    float* out = (float*)d_out;
    char* ws = (char*)d_ws;

    const int nrows = in_sizes[0] / 5;
    const int ntiles = (nrows + 15) / 16;
    const int npairs = (ntiles + 1) / 2;
    unsigned int cap = (ws_size > (size_t)LIST_OFF + 4)
                       ? (unsigned int)((ws_size - LIST_OFF) / 4) : 0u;
    unsigned int* cnt  = (unsigned int*)(ws + CNT_OFF);
    unsigned int* list = (unsigned int*)(ws + LIST_OFF);

    pack_kernel<<<48, 256, 0, stream>>>(W1, b1, W2, b2, W3, b3, ws);

    mfma_main<<<512, 256, 0, stream>>>(x, ws, out, cnt, list, cap,
                                       nrows, npairs);

    rescue_kernel<<<256, 256, 0, stream>>>(x, W1, b1, W2, b2, W3, b3,
                                           ws, out, cap, nrows);
}

// Round 16
// 67.671 us; speedup vs baseline: 4.6452x; 1.1413x over previous
//
#include <hip/hip_runtime.h>

// Per-row MLP 5->120->84->5 + relu + L2-normalize + x!=0 mask.
// R16 = R15 (K16 L1, cvt_pkrtz packs, 2-tile interleave, zero-LDS,
// register-resident weights, wave-parallel rescue) + VALU cuts:
//  1. relu via v_pk_max_f16 AFTER cvt (8 instr/f16x8 instead of 12).
//  2. L2/L3 accumulators born from the first MFMA with C=zero quad
//     (deletes the 56-instr/pair accvgpr zero-init if not already folded).

typedef _Float16 f16x8 __attribute__((ext_vector_type(8)));
typedef _Float16 f16x4 __attribute__((ext_vector_type(4)));
typedef __fp16   hf16x2 __attribute__((ext_vector_type(2)));
typedef float    f32x4 __attribute__((ext_vector_type(4)));

#if __has_builtin(__builtin_amdgcn_mfma_f32_16x16x16f16)
#define HAVE_K16 1
#define MFMA16(a, b, c) __builtin_amdgcn_mfma_f32_16x16x16f16((a), (b), (c), 0, 0, 0)
#elif __has_builtin(__builtin_amdgcn_mfma_f32_16x16x16_f16)
#define HAVE_K16 1
#define MFMA16(a, b, c) __builtin_amdgcn_mfma_f32_16x16x16_f16((a), (b), (c), 0, 0, 0)
#else
#define HAVE_K16 0
#endif
#define MFMA32(a, b, c) __builtin_amdgcn_mfma_f32_16x16x32_f16((a), (b), (c), 0, 0, 0)
#define FZERO ((f32x4){0.f, 0.f, 0.f, 0.f})

#define CNT_OFF  0
#define W1A_OFF  40384       // K16: f16[8][64][4]; K32: f16[8][64][8]
#define W2A_OFF  48576       // f16[24][64][8]       -> ends 73152
#define W3A_OFF  73152       // f16[3][64][8]        -> ends 76224
#define LIST_OFF 76224
#define TAU2     0.04f       // rescue if ||y||^2 < 0.2^2

// cvt then packed-f16 relu: 4 cvt + 4 v_pk_max_f16 (vs 8 fmax + 4 cvt).
__device__ __forceinline__ f16x8 pack_relu8(f32x4 d0, f32x4 d1, float zf) {
    union { f16x8 v; hf16x2 h[4]; } u;
    u.h[0] = __builtin_amdgcn_cvt_pkrtz(d0[0], d0[1]);
    u.h[1] = __builtin_amdgcn_cvt_pkrtz(d0[2], d0[3]);
    u.h[2] = __builtin_amdgcn_cvt_pkrtz(d1[0], d1[1]);
    u.h[3] = __builtin_amdgcn_cvt_pkrtz(d1[2], d1[3]);
    asm("v_pk_max_f16 %0, %0, %1" : "+v"(u.h[0]) : "v"(zf));
    asm("v_pk_max_f16 %0, %0, %1" : "+v"(u.h[1]) : "v"(zf));
    asm("v_pk_max_f16 %0, %0, %1" : "+v"(u.h[2]) : "v"(zf));
    asm("v_pk_max_f16 %0, %0, %1" : "+v"(u.h[3]) : "v"(zf));
    return u.v;
}

// ---------------- pack ----------------
__global__ __launch_bounds__(256) void pack_kernel(
    const float* __restrict__ W1, const float* __restrict__ b1,
    const float* __restrict__ W2, const float* __restrict__ b2,
    const float* __restrict__ W3, const float* __restrict__ b3,
    char* __restrict__ ws)
{
    int i = blockIdx.x * 256 + threadIdx.x;
    if (i == 0) *(unsigned int*)(ws + CNT_OFF) = 0u;
    _Float16* W1a = (_Float16*)(ws + W1A_OFF);
    _Float16* W2a = (_Float16*)(ws + W2A_OFF);
    _Float16* W3a = (_Float16*)(ws + W3A_OFF);

#if HAVE_K16
    // W1a[n][l][j]: K16 A-frag. feat = 16n + (l&15), k = (l>>4)*4 + j.
    if (i < 2048) {
        int n = i >> 8, l = (i >> 2) & 63, j = i & 3;
        int feat = 16*n + (l & 15);
        int k = (l >> 4) * 4 + j;
        float v = 0.f;
        if (feat < 120) {
            if (k < 5) v = W1[feat*5 + k];
            else if (k == 5) v = b1[feat];
        } else if (feat == 120 && k == 5) v = 1.f;
        W1a[i] = (_Float16)v;
    }
#else
    if (i < 4096) {
        int n = i >> 9, l = (i >> 3) & 63, j = i & 7;
        int feat = 16*n + (l & 15);
        int k = (l >> 4) * 8 + j;
        float v = 0.f;
        if (feat < 120) {
            if (k < 5) v = W1[feat*5 + k];
            else if (k == 5) v = b1[feat];
        } else if (feat == 120 && k == 5) v = 1.f;
        W1a[i] = (_Float16)v;
    }
#endif
    // W2a[b=(n2*4+t4)][l][j']: A-frag of W2aug, k-permuted:
    //   f = 32*t4 + 16*(j'>>2) + 4*(l>>4) + (j'&3)
    if (i < 12288) {
        int b = i >> 9, l = (i >> 3) & 63, j = i & 7;
        int n2 = b >> 2, t4 = b & 3;
        int g = 16*n2 + (l & 15);
        int f = 32*t4 + 16*(j >> 2) + 4*(l >> 4) + (j & 3);
        float v = 0.f;
        if (g < 84) {
            if (f < 120) v = W2[g*120 + f];
            else if (f == 120) v = b2[g];
        } else if (g == 84 && f == 120) v = 1.f;
        W2a[i] = (_Float16)v;
    }
    // W3a[t3][l][j']: same k-permutation over h2 features.
    if (i < 1536) {
        int t3 = i >> 9, l = (i >> 3) & 63, j = i & 7;
        int o = l & 15;
        int f = 32*t3 + 16*(j >> 2) + 4*(l >> 4) + (j & 3);
        float v = 0.f;
        if (o < 5) {
            if (f < 84) v = W3[o*84 + f];
            else if (f == 84) v = b3[o];
        }
        W3a[i] = (_Float16)v;
    }
}

// ---------------- main (persistent, zero-LDS, 2-tile interleave) ----------
__global__ __launch_bounds__(256, 2) void mfma_main(
    const float* __restrict__ x, const char* __restrict__ ws,
    float* __restrict__ out,
    unsigned int* __restrict__ cnt, unsigned int* __restrict__ list,
    unsigned int cap, int nrows, int npairs)
{
    const _Float16* W1a = (const _Float16*)(ws + W1A_OFF);
    const _Float16* W2a = (const _Float16*)(ws + W2A_OFF);
    const _Float16* W3a = (const _Float16*)(ws + W3A_OFF);

    const int tid  = threadIdx.x;
    const int w    = tid >> 6, lane = tid & 63;
    const int c    = lane & 15, q = lane >> 4;
    const float zf = 0.f;      // shared zero reg for v_pk_max_f16

    // persistent weight fragments (loaded once per wave)
#if HAVE_K16
    f16x4 w1f[8];
#pragma unroll
    for (int n = 0; n < 8; ++n)  w1f[n] = *(const f16x4*)(W1a + (n*64 + lane)*4);
#else
    f16x8 w1f[8];
#pragma unroll
    for (int n = 0; n < 8; ++n)  w1f[n] = *(const f16x8*)(W1a + (n*64 + lane)*8);
#endif
    f16x8 w2f[24], w3f[3];
#pragma unroll
    for (int b = 0; b < 24; ++b) w2f[b] = *(const f16x8*)(W2a + (b*64 + lane)*8);
#pragma unroll
    for (int t = 0; t < 3; ++t)  w3f[t] = *(const f16x8*)(W3a + (t*64 + lane)*8);

    const int gw = blockIdx.x * 4 + w;
    const int nw = gridDim.x * 4;

    // prefetch x for the first pair (tiles 2p and 2p+1 -> rows 32p+c, +16)
    float nxA[5] = {0.f, 0.f, 0.f, 0.f, 0.f};
    float nxB[5] = {0.f, 0.f, 0.f, 0.f, 0.f};
    if (q == 0 && gw < npairs) {
        long rA = (long)gw * 32 + c;
        long rB = rA + 16;
        if (rA < nrows) {
            const float* xp = x + rA * 5;
            nxA[0]=xp[0]; nxA[1]=xp[1]; nxA[2]=xp[2]; nxA[3]=xp[3]; nxA[4]=xp[4];
        }
        if (rB < nrows) {
            const float* xp = x + rB * 5;
            nxB[0]=xp[0]; nxB[1]=xp[1]; nxB[2]=xp[2]; nxB[3]=xp[3]; nxB[4]=xp[4];
        }
    }

    for (int p = gw; p < npairs; p += nw) {
        const long rowA = (long)p * 32 + c;
        const long rowB = rowA + 16;
        const bool validA = (q == 0) && (rowA < nrows);
        const bool validB = (q == 0) && (rowB < nrows);

        // consume prefetched x
        float xA[5], xB[5];
#pragma unroll
        for (int i = 0; i < 5; ++i) { xA[i] = nxA[i]; xB[i] = nxB[i]; }

        // issue next pair's loads now (hidden under this pair's compute)
#pragma unroll
        for (int i = 0; i < 5; ++i) { nxA[i] = 0.f; nxB[i] = 0.f; }
        {
            const int pn = p + nw;
            if (q == 0 && pn < npairs) {
                long rA = (long)pn * 32 + c;
                long rB = rA + 16;
                if (rA < nrows) {
                    const float* xp = x + rA * 5;
                    nxA[0]=xp[0]; nxA[1]=xp[1]; nxA[2]=xp[2]; nxA[3]=xp[3]; nxA[4]=xp[4];
                }
                if (rB < nrows) {
                    const float* xp = x + rB * 5;
                    nxB[0]=xp[0]; nxB[1]=xp[1]; nxB[2]=xp[2]; nxB[3]=xp[3]; nxB[4]=xp[4];
                }
            }
        }

#if HAVE_K16
        // K16 B-frag: lane holds xaug[c][k=q*4+j].
        // q==0: [x0,x1,x2,x3]; q==1: [x4, 1, 0, 0]; else 0.
        const float x4A = __shfl(xA[4], c, 64);   // broadcast q0's x4 to all q
        const float x4B = __shfl(xB[4], c, 64);
        f16x4 axA, axB;
        {
            union { f16x4 v; hf16x2 h[2]; } ua, ub;
            float aA0 = (q == 0) ? xA[0] : ((q == 1) ? x4A : 0.f);
            float aA1 = (q == 0) ? xA[1] : ((q == 1) ? 1.f  : 0.f);
            float aA2 = (q == 0) ? xA[2] : 0.f;
            float aA3 = (q == 0) ? xA[3] : 0.f;
            float aB0 = (q == 0) ? xB[0] : ((q == 1) ? x4B : 0.f);
            float aB1 = (q == 0) ? xB[1] : ((q == 1) ? 1.f  : 0.f);
            float aB2 = (q == 0) ? xB[2] : 0.f;
            float aB3 = (q == 0) ? xB[3] : 0.f;
            ua.h[0] = __builtin_amdgcn_cvt_pkrtz(aA0, aA1);
            ua.h[1] = __builtin_amdgcn_cvt_pkrtz(aA2, aA3);
            ub.h[0] = __builtin_amdgcn_cvt_pkrtz(aB0, aB1);
            ub.h[1] = __builtin_amdgcn_cvt_pkrtz(aB2, aB3);
            axA = ua.v; axB = ub.v;
        }
#else
        f16x8 axA, axB;
#pragma unroll
        for (int j = 0; j < 8; ++j) { axA[j] = (_Float16)0.f; axB[j] = (_Float16)0.f; }
        if (validA) {
            axA[0]=(_Float16)xA[0]; axA[1]=(_Float16)xA[1]; axA[2]=(_Float16)xA[2];
            axA[3]=(_Float16)xA[3]; axA[4]=(_Float16)xA[4]; axA[5]=(_Float16)1.f;
        }
        if (validB) {
            axB[0]=(_Float16)xB[0]; axB[1]=(_Float16)xB[1]; axB[2]=(_Float16)xB[2];
            axB[3]=(_Float16)xB[3]; axB[4]=(_Float16)xB[4]; axB[5]=(_Float16)1.f;
        }
#endif

        // ---- L1 + fused h1-pack: pb*[t4] (feat = 16n + 4q + j) ----
        f16x8 pbA[4], pbB[4];
#pragma unroll
        for (int t4 = 0; t4 < 4; ++t4) {
#if HAVE_K16
            f32x4 dA0 = MFMA16(w1f[2*t4],     axA, FZERO);
            f32x4 dB0 = MFMA16(w1f[2*t4],     axB, FZERO);
            f32x4 dA1 = MFMA16(w1f[2*t4 + 1], axA, FZERO);
            f32x4 dB1 = MFMA16(w1f[2*t4 + 1], axB, FZERO);
#else
            f32x4 dA0 = MFMA32(w1f[2*t4],     axA, FZERO);
            f32x4 dB0 = MFMA32(w1f[2*t4],     axB, FZERO);
            f32x4 dA1 = MFMA32(w1f[2*t4 + 1], axA, FZERO);
            f32x4 dB1 = MFMA32(w1f[2*t4 + 1], axB, FZERO);
#endif
            pbA[t4] = pack_relu8(dA0, dA1, zf);
            pbB[t4] = pack_relu8(dB0, dB1, zf);
        }

        // ---- L2: acc*[n2] = W2aug . h1^T ; first MFMA born from zero-C ----
        f32x4 accA[6], accB[6];
#pragma unroll
        for (int n2 = 0; n2 < 6; ++n2) {
            accA[n2] = MFMA32(w2f[n2*4 + 0], pbA[0], FZERO);
            accB[n2] = MFMA32(w2f[n2*4 + 0], pbB[0], FZERO);
        }
#pragma unroll
        for (int t4 = 1; t4 < 4; ++t4)
#pragma unroll
            for (int n2 = 0; n2 < 6; ++n2) {
                accA[n2] = MFMA32(w2f[n2*4 + t4], pbA[t4], accA[n2]);
                accB[n2] = MFMA32(w2f[n2*4 + t4], pbB[t4], accB[n2]);
            }

        // ---- pack h2 B-frags ----
        f16x8 phA[3], phB[3];
#pragma unroll
        for (int t3 = 0; t3 < 3; ++t3) {
            phA[t3] = pack_relu8(accA[2*t3], accA[2*t3 + 1], zf);
            phB[t3] = pack_relu8(accB[2*t3], accB[2*t3 + 1], zf);
        }

        // ---- L3 (first MFMA born from zero-C) ----
        f32x4 acyA = MFMA32(w3f[0], phA[0], FZERO);
        f32x4 acyB = MFMA32(w3f[0], phB[0], FZERO);
#pragma unroll
        for (int t3 = 1; t3 < 3; ++t3) {
            acyA = MFMA32(w3f[t3], phA[t3], acyA);
            acyB = MFMA32(w3f[t3], phB[t3], acyB);
        }

        // ---- epilogue (both tiles) ----
        float rA0 = fmaxf(acyA[0], 0.f);
        float rB0 = fmaxf(acyB[0], 0.f);
        float y4A = __shfl(rA0, c + 16, 64);   // out4 lives in q==1, j==0
        float y4B = __shfl(rB0, c + 16, 64);
        if (validA) {
            float y0 = rA0;
            float y1 = fmaxf(acyA[1], 0.f);
            float y2 = fmaxf(acyA[2], 0.f);
            float y3 = fmaxf(acyA[3], 0.f);
            float ss = y0*y0 + y1*y1 + y2*y2 + y3*y3 + y4A*y4A;
            float inv = 1.0f / fmaxf(sqrtf(ss), 1e-12f);
            float* op = out + rowA * 5;
            op[0] = (xA[0] != 0.f) ? 0.f : y0 * inv;
            op[1] = (xA[1] != 0.f) ? 0.f : y1 * inv;
            op[2] = (xA[2] != 0.f) ? 0.f : y2 * inv;
            op[3] = (xA[3] != 0.f) ? 0.f : y3 * inv;
            op[4] = (xA[4] != 0.f) ? 0.f : y4A * inv;
            if (ss < TAU2) {
                unsigned int idx = atomicAdd(cnt, 1u);
                if (idx < cap) list[idx] = (unsigned int)rowA;
            }
        }
        if (validB) {
            float y0 = rB0;
            float y1 = fmaxf(acyB[1], 0.f);
            float y2 = fmaxf(acyB[2], 0.f);
            float y3 = fmaxf(acyB[3], 0.f);
            float ss = y0*y0 + y1*y1 + y2*y2 + y3*y3 + y4B*y4B;
            float inv = 1.0f / fmaxf(sqrtf(ss), 1e-12f);
            float* op = out + rowB * 5;
            op[0] = (xB[0] != 0.f) ? 0.f : y0 * inv;
            op[1] = (xB[1] != 0.f) ? 0.f : y1 * inv;
            op[2] = (xB[2] != 0.f) ? 0.f : y2 * inv;
            op[3] = (xB[3] != 0.f) ? 0.f : y3 * inv;
            op[4] = (xB[4] != 0.f) ? 0.f : y4B * inv;
            if (ss < TAU2) {
                unsigned int idx = atomicAdd(cnt, 1u);
                if (idx < cap) list[idx] = (unsigned int)rowB;
            }
        }
    }
}

// ---------------- rescue (exact f32, WAVE-parallel: 1 wave per row) -------
__global__ __launch_bounds__(256) void rescue_kernel(
    const float* __restrict__ x,
    const float* __restrict__ W1, const float* __restrict__ b1,
    const float* __restrict__ W2, const float* __restrict__ b2,
    const float* __restrict__ W3, const float* __restrict__ b3,
    const char* __restrict__ ws, float* __restrict__ out,
    unsigned int cap, int nrows)
{
    const unsigned int* cnt  = (const unsigned int*)(ws + CNT_OFF);
    const unsigned int* list = (const unsigned int*)(ws + LIST_OFF);
    unsigned int count = *cnt;
    if (count > cap) count = cap;

    const int lane   = threadIdx.x & 63;
    const int wid    = (blockIdx.x * 256 + threadIdx.x) >> 6;
    const int nwaves = (gridDim.x * 256) >> 6;

    const int g1 = lane;                        // h2 output 0..63
    const bool has2 = (lane < 20);
    const int g2 = has2 ? (64 + lane) : 0;      // h2 output 64..83 (clamped)

    for (unsigned int t = wid; t < count; t += nwaves) {
        long row = (long)list[t];
        if (row < 0 || row >= (long)nrows) continue;   // replay-safety guard

        const float* xr = x + row * 5;                 // uniform across wave
        const float xv0 = xr[0], xv1 = xr[1], xv2 = xr[2],
                    xv3 = xr[3], xv4 = xr[4];

        // h2[g] = relu(b2[g] + sum_h W2[g][h] * relu(W1[h].x + b1[h]))
        float acc1 = b2[g1];
        float acc2 = has2 ? b2[g2] : 0.f;
        const float* w2r1 = W2 + (size_t)g1 * 120;
        const float* w2r2 = W2 + (size_t)g2 * 120;
        for (int h = 0; h < 120; ++h) {
            float a = b1[h];
            a = fmaf(W1[h*5 + 0], xv0, a);
            a = fmaf(W1[h*5 + 1], xv1, a);
            a = fmaf(W1[h*5 + 2], xv2, a);
            a = fmaf(W1[h*5 + 3], xv3, a);
            a = fmaf(W1[h*5 + 4], xv4, a);
            a = fmaxf(a, 0.0f);                        // h1[h], uniform
            acc1 = fmaf(w2r1[h], a, acc1);
            acc2 = fmaf(w2r2[h], a, acc2);             // branch-free (clamped)
        }
        float h2a = fmaxf(acc1, 0.f);
        float h2b = has2 ? fmaxf(acc2, 0.f) : 0.f;

        // y[o] = relu(b3[o] + sum_g W3[o][g] * h2[g]) via wave reduction
        float y[5];
#pragma unroll
        for (int o = 0; o < 5; ++o) {
            float p = W3[o*84 + g1] * h2a;
            if (has2) p = fmaf(W3[o*84 + g2], h2b, p);
#pragma unroll
            for (int s = 1; s < 64; s <<= 1) p += __shfl_xor(p, s, 64);
            y[o] = fmaxf(p + b3[o], 0.f);
        }

        if (lane == 0) {
            float ss = y[0]*y[0];
            ss = fmaf(y[1], y[1], ss);
            ss = fmaf(y[2], y[2], ss);
            ss = fmaf(y[3], y[3], ss);
            ss = fmaf(y[4], y[4], ss);
            float inv = 1.0f / fmaxf(sqrtf(ss), 1e-12f);
            float* op = out + row * 5;
#pragma unroll
            for (int o = 0; o < 5; ++o)
                op[o] = (xr[o] != 0.f) ? 0.f : y[o] * inv;
        }
    }
}

// ---------------- launch ----------------
extern "C" void kernel_launch(void* const* d_in, const int* in_sizes, int n_in,
                              void* d_out, int out_size, void* d_ws, size_t ws_size,
                              hipStream_t stream) {
    const float* x  = (const float*)d_in[0];
    const float* W1 = (const float*)d_in[1];
    const float* b1 = (const float*)d_in[2];
    const float* W2 = (const float*)d_in[3];
    const float* b2 = (const float*)d_in[4];
    const float* W3 = (const float*)d_in[5];
    const float* b3 = (const float*)d_in[6];
    float* out = (float*)d_out;
    char* ws = (char*)d_ws;

    const int nrows = in_sizes[0] / 5;
    const int ntiles = (nrows + 15) / 16;
    const int npairs = (ntiles + 1) / 2;
    unsigned int cap = (ws_size > (size_t)LIST_OFF + 4)
                       ? (unsigned int)((ws_size - LIST_OFF) / 4) : 0u;
    unsigned int* cnt  = (unsigned int*)(ws + CNT_OFF);
    unsigned int* list = (unsigned int*)(ws + LIST_OFF);

    pack_kernel<<<48, 256, 0, stream>>>(W1, b1, W2, b2, W3, b3, ws);

    mfma_main<<<512, 256, 0, stream>>>(x, ws, out, cnt, list, cap,
                                       nrows, npairs);

    rescue_kernel<<<256, 256, 0, stream>>>(x, W1, b1, W2, b2, W3, b3,
                                           ws, out, cap, nrows);
}

// Round 17
// 66.010 us; speedup vs baseline: 4.7621x; 1.0252x over previous
//
#include <hip/hip_runtime.h>

// Per-row MLP 5->120->84->5 + relu + L2-normalize + x!=0 mask.
// R17 = R16 (K16 L1, cvt_pkrtz + v_pk_max_f16 packs, zero-C-born accs,
// 2-tile interleave, zero-LDS, register-resident weights, wave-parallel
// rescue) + three trims:
//  1. Epilogue via v_rsq_f32 (rescued rows are exactly recomputed, so the
//     eps-clamp/rsq(0) edge cases never reach the final output).
//  2. s_setprio(1) around the L2/L3 MFMA clusters (waves are barrier-free
//     and phase-drifted -> scheduler can favor the MFMA-phase wave; the
//     m191-attn regime, not the lockstep-GEMM null).
//  3. 32-bit row indexing (rows < 2^21).

typedef _Float16 f16x8 __attribute__((ext_vector_type(8)));
typedef _Float16 f16x4 __attribute__((ext_vector_type(4)));
typedef __fp16   hf16x2 __attribute__((ext_vector_type(2)));
typedef float    f32x4 __attribute__((ext_vector_type(4)));

#if __has_builtin(__builtin_amdgcn_mfma_f32_16x16x16f16)
#define HAVE_K16 1
#define MFMA16(a, b, c) __builtin_amdgcn_mfma_f32_16x16x16f16((a), (b), (c), 0, 0, 0)
#elif __has_builtin(__builtin_amdgcn_mfma_f32_16x16x16_f16)
#define HAVE_K16 1
#define MFMA16(a, b, c) __builtin_amdgcn_mfma_f32_16x16x16_f16((a), (b), (c), 0, 0, 0)
#else
#define HAVE_K16 0
#endif
#define MFMA32(a, b, c) __builtin_amdgcn_mfma_f32_16x16x32_f16((a), (b), (c), 0, 0, 0)
#define FZERO ((f32x4){0.f, 0.f, 0.f, 0.f})

#if __has_builtin(__builtin_amdgcn_rsqf)
#define RSQ(x) __builtin_amdgcn_rsqf(x)
#else
#define RSQ(x) (1.0f / sqrtf(x))
#endif

#define CNT_OFF  0
#define W1A_OFF  40384       // K16: f16[8][64][4]; K32: f16[8][64][8]
#define W2A_OFF  48576       // f16[24][64][8]       -> ends 73152
#define W3A_OFF  73152       // f16[3][64][8]        -> ends 76224
#define LIST_OFF 76224
#define TAU2     0.04f       // rescue if ||y||^2 < 0.2^2

// cvt then packed-f16 relu: 4 cvt + 4 v_pk_max_f16.
__device__ __forceinline__ f16x8 pack_relu8(f32x4 d0, f32x4 d1, float zf) {
    union { f16x8 v; hf16x2 h[4]; } u;
    u.h[0] = __builtin_amdgcn_cvt_pkrtz(d0[0], d0[1]);
    u.h[1] = __builtin_amdgcn_cvt_pkrtz(d0[2], d0[3]);
    u.h[2] = __builtin_amdgcn_cvt_pkrtz(d1[0], d1[1]);
    u.h[3] = __builtin_amdgcn_cvt_pkrtz(d1[2], d1[3]);
    asm("v_pk_max_f16 %0, %0, %1" : "+v"(u.h[0]) : "v"(zf));
    asm("v_pk_max_f16 %0, %0, %1" : "+v"(u.h[1]) : "v"(zf));
    asm("v_pk_max_f16 %0, %0, %1" : "+v"(u.h[2]) : "v"(zf));
    asm("v_pk_max_f16 %0, %0, %1" : "+v"(u.h[3]) : "v"(zf));
    return u.v;
}

// ---------------- pack ----------------
__global__ __launch_bounds__(256) void pack_kernel(
    const float* __restrict__ W1, const float* __restrict__ b1,
    const float* __restrict__ W2, const float* __restrict__ b2,
    const float* __restrict__ W3, const float* __restrict__ b3,
    char* __restrict__ ws)
{
    int i = blockIdx.x * 256 + threadIdx.x;
    if (i == 0) *(unsigned int*)(ws + CNT_OFF) = 0u;
    _Float16* W1a = (_Float16*)(ws + W1A_OFF);
    _Float16* W2a = (_Float16*)(ws + W2A_OFF);
    _Float16* W3a = (_Float16*)(ws + W3A_OFF);

#if HAVE_K16
    // W1a[n][l][j]: K16 A-frag. feat = 16n + (l&15), k = (l>>4)*4 + j.
    if (i < 2048) {
        int n = i >> 8, l = (i >> 2) & 63, j = i & 3;
        int feat = 16*n + (l & 15);
        int k = (l >> 4) * 4 + j;
        float v = 0.f;
        if (feat < 120) {
            if (k < 5) v = W1[feat*5 + k];
            else if (k == 5) v = b1[feat];
        } else if (feat == 120 && k == 5) v = 1.f;
        W1a[i] = (_Float16)v;
    }
#else
    if (i < 4096) {
        int n = i >> 9, l = (i >> 3) & 63, j = i & 7;
        int feat = 16*n + (l & 15);
        int k = (l >> 4) * 8 + j;
        float v = 0.f;
        if (feat < 120) {
            if (k < 5) v = W1[feat*5 + k];
            else if (k == 5) v = b1[feat];
        } else if (feat == 120 && k == 5) v = 1.f;
        W1a[i] = (_Float16)v;
    }
#endif
    // W2a[b=(n2*4+t4)][l][j']: A-frag of W2aug, k-permuted:
    //   f = 32*t4 + 16*(j'>>2) + 4*(l>>4) + (j'&3)
    if (i < 12288) {
        int b = i >> 9, l = (i >> 3) & 63, j = i & 7;
        int n2 = b >> 2, t4 = b & 3;
        int g = 16*n2 + (l & 15);
        int f = 32*t4 + 16*(j >> 2) + 4*(l >> 4) + (j & 3);
        float v = 0.f;
        if (g < 84) {
            if (f < 120) v = W2[g*120 + f];
            else if (f == 120) v = b2[g];
        } else if (g == 84 && f == 120) v = 1.f;
        W2a[i] = (_Float16)v;
    }
    // W3a[t3][l][j']: same k-permutation over h2 features.
    if (i < 1536) {
        int t3 = i >> 9, l = (i >> 3) & 63, j = i & 7;
        int o = l & 15;
        int f = 32*t3 + 16*(j >> 2) + 4*(l >> 4) + (j & 3);
        float v = 0.f;
        if (o < 5) {
            if (f < 84) v = W3[o*84 + f];
            else if (f == 84) v = b3[o];
        }
        W3a[i] = (_Float16)v;
    }
}

// ---------------- main (persistent, zero-LDS, 2-tile interleave) ----------
__global__ __launch_bounds__(256, 2) void mfma_main(
    const float* __restrict__ x, const char* __restrict__ ws,
    float* __restrict__ out,
    unsigned int* __restrict__ cnt, unsigned int* __restrict__ list,
    unsigned int cap, int nrows, int npairs)
{
    const _Float16* W1a = (const _Float16*)(ws + W1A_OFF);
    const _Float16* W2a = (const _Float16*)(ws + W2A_OFF);
    const _Float16* W3a = (const _Float16*)(ws + W3A_OFF);

    const int tid  = threadIdx.x;
    const int w    = tid >> 6, lane = tid & 63;
    const int c    = lane & 15, q = lane >> 4;
    const float zf = 0.f;      // shared zero reg for v_pk_max_f16

    // persistent weight fragments (loaded once per wave)
#if HAVE_K16
    f16x4 w1f[8];
#pragma unroll
    for (int n = 0; n < 8; ++n)  w1f[n] = *(const f16x4*)(W1a + (n*64 + lane)*4);
#else
    f16x8 w1f[8];
#pragma unroll
    for (int n = 0; n < 8; ++n)  w1f[n] = *(const f16x8*)(W1a + (n*64 + lane)*8);
#endif
    f16x8 w2f[24], w3f[3];
#pragma unroll
    for (int b = 0; b < 24; ++b) w2f[b] = *(const f16x8*)(W2a + (b*64 + lane)*8);
#pragma unroll
    for (int t = 0; t < 3; ++t)  w3f[t] = *(const f16x8*)(W3a + (t*64 + lane)*8);

    const int gw = blockIdx.x * 4 + w;
    const int nw = gridDim.x * 4;

    // prefetch x for the first pair (tiles 2p and 2p+1 -> rows 32p+c, +16)
    float nxA[5] = {0.f, 0.f, 0.f, 0.f, 0.f};
    float nxB[5] = {0.f, 0.f, 0.f, 0.f, 0.f};
    if (q == 0 && gw < npairs) {
        int rA = gw * 32 + c;
        int rB = rA + 16;
        if (rA < nrows) {
            const float* xp = x + rA * 5;
            nxA[0]=xp[0]; nxA[1]=xp[1]; nxA[2]=xp[2]; nxA[3]=xp[3]; nxA[4]=xp[4];
        }
        if (rB < nrows) {
            const float* xp = x + rB * 5;
            nxB[0]=xp[0]; nxB[1]=xp[1]; nxB[2]=xp[2]; nxB[3]=xp[3]; nxB[4]=xp[4];
        }
    }

    for (int p = gw; p < npairs; p += nw) {
        const int rowA = p * 32 + c;
        const int rowB = rowA + 16;
        const bool validA = (q == 0) && (rowA < nrows);
        const bool validB = (q == 0) && (rowB < nrows);

        // consume prefetched x
        float xA[5], xB[5];
#pragma unroll
        for (int i = 0; i < 5; ++i) { xA[i] = nxA[i]; xB[i] = nxB[i]; }

        // issue next pair's loads now (hidden under this pair's compute)
#pragma unroll
        for (int i = 0; i < 5; ++i) { nxA[i] = 0.f; nxB[i] = 0.f; }
        {
            const int pn = p + nw;
            if (q == 0 && pn < npairs) {
                int rA = pn * 32 + c;
                int rB = rA + 16;
                if (rA < nrows) {
                    const float* xp = x + rA * 5;
                    nxA[0]=xp[0]; nxA[1]=xp[1]; nxA[2]=xp[2]; nxA[3]=xp[3]; nxA[4]=xp[4];
                }
                if (rB < nrows) {
                    const float* xp = x + rB * 5;
                    nxB[0]=xp[0]; nxB[1]=xp[1]; nxB[2]=xp[2]; nxB[3]=xp[3]; nxB[4]=xp[4];
                }
            }
        }

#if HAVE_K16
        // K16 B-frag: lane holds xaug[c][k=q*4+j].
        // q==0: [x0,x1,x2,x3]; q==1: [x4, 1, 0, 0]; else 0.
        const float x4A = __shfl(xA[4], c, 64);   // broadcast q0's x4 to all q
        const float x4B = __shfl(xB[4], c, 64);
        f16x4 axA, axB;
        {
            union { f16x4 v; hf16x2 h[2]; } ua, ub;
            float aA0 = (q == 0) ? xA[0] : ((q == 1) ? x4A : 0.f);
            float aA1 = (q == 0) ? xA[1] : ((q == 1) ? 1.f  : 0.f);
            float aA2 = (q == 0) ? xA[2] : 0.f;
            float aA3 = (q == 0) ? xA[3] : 0.f;
            float aB0 = (q == 0) ? xB[0] : ((q == 1) ? x4B : 0.f);
            float aB1 = (q == 0) ? xB[1] : ((q == 1) ? 1.f  : 0.f);
            float aB2 = (q == 0) ? xB[2] : 0.f;
            float aB3 = (q == 0) ? xB[3] : 0.f;
            ua.h[0] = __builtin_amdgcn_cvt_pkrtz(aA0, aA1);
            ua.h[1] = __builtin_amdgcn_cvt_pkrtz(aA2, aA3);
            ub.h[0] = __builtin_amdgcn_cvt_pkrtz(aB0, aB1);
            ub.h[1] = __builtin_amdgcn_cvt_pkrtz(aB2, aB3);
            axA = ua.v; axB = ub.v;
        }
#else
        f16x8 axA, axB;
#pragma unroll
        for (int j = 0; j < 8; ++j) { axA[j] = (_Float16)0.f; axB[j] = (_Float16)0.f; }
        if (validA) {
            axA[0]=(_Float16)xA[0]; axA[1]=(_Float16)xA[1]; axA[2]=(_Float16)xA[2];
            axA[3]=(_Float16)xA[3]; axA[4]=(_Float16)xA[4]; axA[5]=(_Float16)1.f;
        }
        if (validB) {
            axB[0]=(_Float16)xB[0]; axB[1]=(_Float16)xB[1]; axB[2]=(_Float16)xB[2];
            axB[3]=(_Float16)xB[3]; axB[4]=(_Float16)xB[4]; axB[5]=(_Float16)1.f;
        }
#endif

        // ---- L1 + fused h1-pack: pb*[t4] (feat = 16n + 4q + j) ----
        f16x8 pbA[4], pbB[4];
#pragma unroll
        for (int t4 = 0; t4 < 4; ++t4) {
#if HAVE_K16
            f32x4 dA0 = MFMA16(w1f[2*t4],     axA, FZERO);
            f32x4 dB0 = MFMA16(w1f[2*t4],     axB, FZERO);
            f32x4 dA1 = MFMA16(w1f[2*t4 + 1], axA, FZERO);
            f32x4 dB1 = MFMA16(w1f[2*t4 + 1], axB, FZERO);
#else
            f32x4 dA0 = MFMA32(w1f[2*t4],     axA, FZERO);
            f32x4 dB0 = MFMA32(w1f[2*t4],     axB, FZERO);
            f32x4 dA1 = MFMA32(w1f[2*t4 + 1], axA, FZERO);
            f32x4 dB1 = MFMA32(w1f[2*t4 + 1], axB, FZERO);
#endif
            pbA[t4] = pack_relu8(dA0, dA1, zf);
            pbB[t4] = pack_relu8(dB0, dB1, zf);
        }

        // ---- L2: acc*[n2] = W2aug . h1^T ; first MFMA born from zero-C ----
        __builtin_amdgcn_s_setprio(1);
        f32x4 accA[6], accB[6];
#pragma unroll
        for (int n2 = 0; n2 < 6; ++n2) {
            accA[n2] = MFMA32(w2f[n2*4 + 0], pbA[0], FZERO);
            accB[n2] = MFMA32(w2f[n2*4 + 0], pbB[0], FZERO);
        }
#pragma unroll
        for (int t4 = 1; t4 < 4; ++t4)
#pragma unroll
            for (int n2 = 0; n2 < 6; ++n2) {
                accA[n2] = MFMA32(w2f[n2*4 + t4], pbA[t4], accA[n2]);
                accB[n2] = MFMA32(w2f[n2*4 + t4], pbB[t4], accB[n2]);
            }
        __builtin_amdgcn_s_setprio(0);

        // ---- pack h2 B-frags ----
        f16x8 phA[3], phB[3];
#pragma unroll
        for (int t3 = 0; t3 < 3; ++t3) {
            phA[t3] = pack_relu8(accA[2*t3], accA[2*t3 + 1], zf);
            phB[t3] = pack_relu8(accB[2*t3], accB[2*t3 + 1], zf);
        }

        // ---- L3 (first MFMA born from zero-C) ----
        __builtin_amdgcn_s_setprio(1);
        f32x4 acyA = MFMA32(w3f[0], phA[0], FZERO);
        f32x4 acyB = MFMA32(w3f[0], phB[0], FZERO);
#pragma unroll
        for (int t3 = 1; t3 < 3; ++t3) {
            acyA = MFMA32(w3f[t3], phA[t3], acyA);
            acyB = MFMA32(w3f[t3], phB[t3], acyB);
        }
        __builtin_amdgcn_s_setprio(0);

        // ---- epilogue (both tiles) ----
        float rA0 = fmaxf(acyA[0], 0.f);
        float rB0 = fmaxf(acyB[0], 0.f);
        float y4A = __shfl(rA0, c + 16, 64);   // out4 lives in q==1, j==0
        float y4B = __shfl(rB0, c + 16, 64);
        if (validA) {
            float y0 = rA0;
            float y1 = fmaxf(acyA[1], 0.f);
            float y2 = fmaxf(acyA[2], 0.f);
            float y3 = fmaxf(acyA[3], 0.f);
            float ss = y0*y0 + y1*y1 + y2*y2 + y3*y3 + y4A*y4A;
            float inv = RSQ(fmaxf(ss, 1e-30f));  // rescued rows overwritten
            float* op = out + rowA * 5;
            op[0] = (xA[0] != 0.f) ? 0.f : y0 * inv;
            op[1] = (xA[1] != 0.f) ? 0.f : y1 * inv;
            op[2] = (xA[2] != 0.f) ? 0.f : y2 * inv;
            op[3] = (xA[3] != 0.f) ? 0.f : y3 * inv;
            op[4] = (xA[4] != 0.f) ? 0.f : y4A * inv;
            if (ss < TAU2) {
                unsigned int idx = atomicAdd(cnt, 1u);
                if (idx < cap) list[idx] = (unsigned int)rowA;
            }
        }
        if (validB) {
            float y0 = rB0;
            float y1 = fmaxf(acyB[1], 0.f);
            float y2 = fmaxf(acyB[2], 0.f);
            float y3 = fmaxf(acyB[3], 0.f);
            float ss = y0*y0 + y1*y1 + y2*y2 + y3*y3 + y4B*y4B;
            float inv = RSQ(fmaxf(ss, 1e-30f));
            float* op = out + rowB * 5;
            op[0] = (xB[0] != 0.f) ? 0.f : y0 * inv;
            op[1] = (xB[1] != 0.f) ? 0.f : y1 * inv;
            op[2] = (xB[2] != 0.f) ? 0.f : y2 * inv;
            op[3] = (xB[3] != 0.f) ? 0.f : y3 * inv;
            op[4] = (xB[4] != 0.f) ? 0.f : y4B * inv;
            if (ss < TAU2) {
                unsigned int idx = atomicAdd(cnt, 1u);
                if (idx < cap) list[idx] = (unsigned int)rowB;
            }
        }
    }
}

// ---------------- rescue (exact f32, WAVE-parallel: 1 wave per row) -------
__global__ __launch_bounds__(256) void rescue_kernel(
    const float* __restrict__ x,
    const float* __restrict__ W1, const float* __restrict__ b1,
    const float* __restrict__ W2, const float* __restrict__ b2,
    const float* __restrict__ W3, const float* __restrict__ b3,
    const char* __restrict__ ws, float* __restrict__ out,
    unsigned int cap, int nrows)
{
    const unsigned int* cnt  = (const unsigned int*)(ws + CNT_OFF);
    const unsigned int* list = (const unsigned int*)(ws + LIST_OFF);
    unsigned int count = *cnt;
    if (count > cap) count = cap;

    const int lane   = threadIdx.x & 63;
    const int wid    = (blockIdx.x * 256 + threadIdx.x) >> 6;
    const int nwaves = (gridDim.x * 256) >> 6;

    const int g1 = lane;                        // h2 output 0..63
    const bool has2 = (lane < 20);
    const int g2 = has2 ? (64 + lane) : 0;      // h2 output 64..83 (clamped)

    for (unsigned int t = wid; t < count; t += nwaves) {
        long row = (long)list[t];
        if (row < 0 || row >= (long)nrows) continue;   // replay-safety guard

        const float* xr = x + row * 5;                 // uniform across wave
        const float xv0 = xr[0], xv1 = xr[1], xv2 = xr[2],
                    xv3 = xr[3], xv4 = xr[4];

        // h2[g] = relu(b2[g] + sum_h W2[g][h] * relu(W1[h].x + b1[h]))
        float acc1 = b2[g1];
        float acc2 = has2 ? b2[g2] : 0.f;
        const float* w2r1 = W2 + (size_t)g1 * 120;
        const float* w2r2 = W2 + (size_t)g2 * 120;
        for (int h = 0; h < 120; ++h) {
            float a = b1[h];
            a = fmaf(W1[h*5 + 0], xv0, a);
            a = fmaf(W1[h*5 + 1], xv1, a);
            a = fmaf(W1[h*5 + 2], xv2, a);
            a = fmaf(W1[h*5 + 3], xv3, a);
            a = fmaf(W1[h*5 + 4], xv4, a);
            a = fmaxf(a, 0.0f);                        // h1[h], uniform
            acc1 = fmaf(w2r1[h], a, acc1);
            acc2 = fmaf(w2r2[h], a, acc2);             // branch-free (clamped)
        }
        float h2a = fmaxf(acc1, 0.f);
        float h2b = has2 ? fmaxf(acc2, 0.f) : 0.f;

        // y[o] = relu(b3[o] + sum_g W3[o][g] * h2[g]) via wave reduction
        float y[5];
#pragma unroll
        for (int o = 0; o < 5; ++o) {
            float p = W3[o*84 + g1] * h2a;
            if (has2) p = fmaf(W3[o*84 + g2], h2b, p);
#pragma unroll
            for (int s = 1; s < 64; s <<= 1) p += __shfl_xor(p, s, 64);
            y[o] = fmaxf(p + b3[o], 0.f);
        }

        if (lane == 0) {
            float ss = y[0]*y[0];
            ss = fmaf(y[1], y[1], ss);
            ss = fmaf(y[2], y[2], ss);
            ss = fmaf(y[3], y[3], ss);
            ss = fmaf(y[4], y[4], ss);
            float inv = 1.0f / fmaxf(sqrtf(ss), 1e-12f);
            float* op = out + row * 5;
#pragma unroll
            for (int o = 0; o < 5; ++o)
                op[o] = (xr[o] != 0.f) ? 0.f : y[o] * inv;
        }
    }
}

// ---------------- launch ----------------
extern "C" void kernel_launch(void* const* d_in, const int* in_sizes, int n_in,
                              void* d_out, int out_size, void* d_ws, size_t ws_size,
                              hipStream_t stream) {
    const float* x  = (const float*)d_in[0];
    const float* W1 = (const float*)d_in[1];
    const float* b1 = (const float*)d_in[2];
    const float* W2 = (const float*)d_in[3];
    const float* b2 = (const float*)d_in[4];
    const float* W3 = (const float*)d_in[5];
    const float* b3 = (const float*)d_in[6];
    float* out = (float*)d_out;
    char* ws = (char*)d_ws;

    const int nrows = in_sizes[0] / 5;
    const int ntiles = (nrows + 15) / 16;
    const int npairs = (ntiles + 1) / 2;
    unsigned int cap = (ws_size > (size_t)LIST_OFF + 4)
                       ? (unsigned int)((ws_size - LIST_OFF) / 4) : 0u;
    unsigned int* cnt  = (unsigned int*)(ws + CNT_OFF);
    unsigned int* list = (unsigned int*)(ws + LIST_OFF);

    pack_kernel<<<48, 256, 0, stream>>>(W1, b1, W2, b2, W3, b3, ws);

    mfma_main<<<512, 256, 0, stream>>>(x, ws, out, cnt, list, cap,
                                       nrows, npairs);

    rescue_kernel<<<256, 256, 0, stream>>>(x, W1, b1, W2, b2, W3, b3,
                                           ws, out, cap, nrows);
}